// Round 1
// 264.794 us; speedup vs baseline: 1.0538x; 1.0538x over previous
//
#include <hip/hip_runtime.h>
#include <hip/hip_bf16.h>
#include <math.h>

#define S_LEN 2048
#define DIN   2048
#define NH    32
#define NKV   8
#define HD    64
#define DOUT  2048        // NH*HD
#define QKVN  3072        // DOUT + 2*KVD
#define KOFF  2048        // k col offset in qkv
#define VOFF  2560        // v col offset in qkv

typedef __attribute__((ext_vector_type(8))) short short8v;    // 8 bf16 (4 VGPRs)
typedef __attribute__((ext_vector_type(8))) unsigned short ushort8v;
typedef __attribute__((ext_vector_type(4))) unsigned short ushort4v;
typedef __attribute__((ext_vector_type(4))) float float4v;
typedef __attribute__((ext_vector_type(16))) float float16v;

__device__ __forceinline__ float bf2f(unsigned short u) {
    union { float f; unsigned u; } c; c.u = ((unsigned)u) << 16; return c.f;
}
__device__ __forceinline__ unsigned short f2bf(float f) {
    union { float f; unsigned u; } c; c.f = f;
    unsigned r = c.u + 0x7fffu + ((c.u >> 16) & 1u);   // RNE
    return (unsigned short)(r >> 16);
}
__device__ __forceinline__ unsigned short f2h(float f) {
    union { _Float16 h; unsigned short u; } c; c.h = (_Float16)f; return c.u;
}
__device__ __forceinline__ float h2f(unsigned short u) {
    union { _Float16 h; unsigned short u; } c; c.u = u; return (float)c.h;
}
__device__ __forceinline__ unsigned cvtpk(float lo, float hi) {
    unsigned r;
    asm("v_cvt_pk_bf16_f32 %0, %1, %2" : "=v"(r) : "v"(lo), "v"(hi));
    return r;
}

// ---------------------------------------------------------------------------
// Fused preprocessing, ONE launch, grid sections:
//   [0, 6144)        : Wq|Wk|Wv fp32 [K][N] -> bf16 [N][K] into W1 (32x32 tiles)
//   [6144, 10240)    : Wo transpose into WoT
//   [10240, 14336)   : x fp32 -> bf16 cast into XB
// ---------------------------------------------------------------------------
__global__ __launch_bounds__(256) void prep(const float* __restrict__ Wq,
                                            const float* __restrict__ Wk,
                                            const float* __restrict__ Wv,
                                            const float* __restrict__ Wo,
                                            const float* __restrict__ x,
                                            unsigned short* __restrict__ W1,
                                            unsigned short* __restrict__ WoT,
                                            unsigned short* __restrict__ XB) {
    __shared__ float t[32][33];
    const int a = blockIdx.x;
    const int tx = threadIdx.x & 31, ty = threadIdx.x >> 5;
    if (a < 6144) {                       // qkv weights: grid (96, 64)
        const int n0 = (a % 96) * 32, k0 = (a / 96) * 32;
        const float* src; int nn0, Nsrc;
        if (n0 < KOFF)      { src = Wq; nn0 = n0;        Nsrc = DOUT; }
        else if (n0 < VOFF) { src = Wk; nn0 = n0 - KOFF; Nsrc = 512; }
        else                { src = Wv; nn0 = n0 - VOFF; Nsrc = 512; }
#pragma unroll
        for (int j = ty; j < 32; j += 8)
            t[j][tx] = src[(size_t)(k0 + j) * Nsrc + nn0 + tx];
        __syncthreads();
#pragma unroll
        for (int j = ty; j < 32; j += 8)
            W1[(size_t)(n0 + j) * DIN + k0 + tx] = f2bf(t[tx][j]);
    } else if (a < 10240) {               // Wo: grid (64, 64), K=DOUT rows, N=DIN
        const int b = a - 6144;
        const int n0 = (b % 64) * 32, k0 = (b / 64) * 32;
#pragma unroll
        for (int j = ty; j < 32; j += 8)
            t[j][tx] = Wo[(size_t)(k0 + j) * DIN + n0 + tx];
        __syncthreads();
#pragma unroll
        for (int j = ty; j < 32; j += 8)
            WoT[(size_t)(n0 + j) * DOUT + k0 + tx] = f2bf(t[tx][j]);
    } else {                              // x cast: 4096 blocks x 1024 elems
        const int i = (a - 10240) * 1024 + threadIdx.x * 4;
        float4 v = *(const float4*)(x + i);
        XB[i + 0] = f2bf(v.x); XB[i + 1] = f2bf(v.y);
        XB[i + 2] = f2bf(v.z); XB[i + 3] = f2bf(v.w);
    }
}

// ---------------------------------------------------------------------------
// bf16 MFMA GEMM, 128x64 tile, BK=32, 4 waves stacked in M (wave = 32x64).
// FUSE=1: bf16 out + per-head RMSNorm+RoPE epilogue (block col = one head).
// FUSE=0: fp32 out, plain.
// ---------------------------------------------------------------------------
template <int FUSE>
__global__ __launch_bounds__(256) void gemm64(const unsigned short* __restrict__ A,
                                              const unsigned short* __restrict__ Bt,
                                              void* __restrict__ Cv, int M, int N, int K,
                                              const float* __restrict__ qnw,
                                              const float* __restrict__ knw,
                                              const float* __restrict__ cosb,
                                              const float* __restrict__ sinb) {
    __shared__ __attribute__((aligned(16))) unsigned short As[128 * 32];
    __shared__ __attribute__((aligned(16))) unsigned short Bs[64 * 32];
    const int tid = threadIdx.x, lane = tid & 63, w = tid >> 6;
    const int bm = blockIdx.y * 128, bn = blockIdx.x * 64;
    const int wm = w * 32;

    float4v acc[2][4];
#pragma unroll
    for (int i = 0; i < 2; i++)
#pragma unroll
        for (int j = 0; j < 4; j++) acc[i][j] = (float4v){0.f, 0.f, 0.f, 0.f};

    const int lr = lane >> 2, lc = (lane & 3) * 8;
    const unsigned short* Ag0 = A + (size_t)(bm + w * 32 + lr) * K + lc;
    const unsigned short* Ag1 = Ag0 + (size_t)16 * K;
    const unsigned short* Bg  = Bt + (size_t)(bn + w * 16 + lr) * K + lc;
    unsigned short* Al0 = As + (w * 32) * 32;
    unsigned short* Al1 = As + (w * 32 + 16) * 32;
    unsigned short* Bl  = Bs + (w * 16) * 32;

    const int frow = lane & 15, fk = (lane >> 4) * 8;

    for (int k0 = 0; k0 < K; k0 += 32) {
        __syncthreads();
        __builtin_amdgcn_global_load_lds(
            (const __attribute__((address_space(1))) void*)(Ag0 + k0),
            (__attribute__((address_space(3))) void*)Al0, 16, 0, 0);
        __builtin_amdgcn_global_load_lds(
            (const __attribute__((address_space(1))) void*)(Ag1 + k0),
            (__attribute__((address_space(3))) void*)Al1, 16, 0, 0);
        __builtin_amdgcn_global_load_lds(
            (const __attribute__((address_space(1))) void*)(Bg + k0),
            (__attribute__((address_space(3))) void*)Bl, 16, 0, 0);
        __syncthreads();

        short8v af[2], bf[4];
#pragma unroll
        for (int fm = 0; fm < 2; fm++)
            af[fm] = *(const short8v*)(As + (wm + fm * 16 + frow) * 32 + fk);
#pragma unroll
        for (int fn = 0; fn < 4; fn++)
            bf[fn] = *(const short8v*)(Bs + (fn * 16 + frow) * 32 + fk);
#pragma unroll
        for (int fm = 0; fm < 2; fm++)
#pragma unroll
            for (int fn = 0; fn < 4; fn++)
                acc[fm][fn] = __builtin_amdgcn_mfma_f32_16x16x32_bf16(
                    af[fm], bf[fn], acc[fm][fn], 0, 0, 0);
    }

    const int quad = lane >> 4, col16 = lane & 15;
    if constexpr (FUSE == 1) {
        unsigned short* C = (unsigned short*)Cv;
        const int head = bn >> 6;                 // one head per block col
        if (head < 40) {
            const float* nw = (head < 32) ? qnw : knw;
            float wv[4];
#pragma unroll
            for (int fn = 0; fn < 4; fn++) wv[fn] = nw[fn * 16 + col16];
#pragma unroll
            for (int fm = 0; fm < 2; fm++)
#pragma unroll
                for (int r = 0; r < 4; r++) {
                    float x0 = acc[fm][0][r], x1 = acc[fm][1][r];
                    float x2 = acc[fm][2][r], x3 = acc[fm][3][r];
                    float ss = x0 * x0 + x1 * x1 + x2 * x2 + x3 * x3;
                    ss += __shfl_xor(ss, 1); ss += __shfl_xor(ss, 2);
                    ss += __shfl_xor(ss, 4); ss += __shfl_xor(ss, 8);
                    const float inv = rsqrtf(ss * (1.0f / 64.0f) + 1e-6f);
                    float xn[4] = {x0 * inv * wv[0], x1 * inv * wv[1],
                                   x2 * inv * wv[2], x3 * inv * wv[3]};
                    const int row = bm + wm + fm * 16 + quad * 4 + r;
                    const float* cr = cosb + (size_t)row * HD;
                    const float* sr = sinb + (size_t)row * HD;
#pragma unroll
                    for (int fn = 0; fn < 4; fn++) {
                        const float rot = (fn < 2) ? -xn[fn + 2] : xn[fn - 2];
                        const float res = xn[fn] * cr[fn * 16 + col16] +
                                          rot * sr[fn * 16 + col16];
                        C[(size_t)row * N + bn + fn * 16 + col16] = f2bf(res);
                    }
                }
        } else {
#pragma unroll
            for (int fm = 0; fm < 2; fm++)
#pragma unroll
                for (int fn = 0; fn < 4; fn++)
#pragma unroll
                    for (int r = 0; r < 4; r++)
                        C[(size_t)(bm + wm + fm * 16 + quad * 4 + r) * N +
                          bn + fn * 16 + col16] = f2bf(acc[fm][fn][r]);
        }
    } else {
        float* C = (float*)Cv;
#pragma unroll
        for (int fm = 0; fm < 2; fm++)
#pragma unroll
            for (int fn = 0; fn < 4; fn++)
#pragma unroll
                for (int r = 0; r < 4; r++)
                    C[(size_t)(bm + wm + fm * 16 + quad * 4 + r) * N +
                      bn + fn * 16 + col16] = acc[fm][fn][r];
    }
}

// ---------------------------------------------------------------------------
// MFMA flash attention v5 (causal, GQA), fixed-max softmax.
//   * Swapped QK^T (mfma(K, Q), 32x32x16): S^T lands with q = lane&31, keys in
//     regs -> softmax fully lane-local; P packed to bf16 in-register via
//     v_cvt_pk_bf16_f32 and redistributed lane<->lane^32 with shfl_xor into
//     PV A-frags. NO P LDS round-trip (Ps buffer, 32 b16 writes + 4 b128
//     reads + ~160 convert VALU per tile: all gone).
//   * Causal load balance: block = (g, pair p, chunk s). qtile p is paired
//     with qtile 63-p: nt(p)+nt(63-p) == 33 for all p, chunked 17/16 ->
//     all 512 blocks have identical work, no straggler tail. K/V staging
//     runs over the concatenated tile stream (pointers depend only on tile
//     index); at the qa->qb boundary: flush qa partial, reset acc, reload Q.
//   * qa (rows < 1024) is fully contained in chunk 0 -> single partial;
//     combine only merges two partials for rows >= 1024.
// LDS = 2 x 64 x KSTR shorts = 22.5 KB. 512 blocks, 2/CU, 8 waves/CU flat.
// ---------------------------------------------------------------------------
#define KSTR 88    // K/V LDS row stride (shorts)

__global__ __launch_bounds__(256) void flash_part(const unsigned short* __restrict__ qb,
                                                  const unsigned short* __restrict__ kb,
                                                  const unsigned short* __restrict__ vb,
                                                  unsigned short* __restrict__ Op,
                                                  float* __restrict__ Lp) {
    __shared__ __attribute__((aligned(16))) unsigned short Ks[64 * KSTR];
    __shared__ __attribute__((aligned(16))) unsigned short Vt[64 * KSTR];

    const int tid = threadIdx.x, lane = tid & 63, w = tid >> 6;
    const int sl = lane & 31, hi = lane >> 5, hi8 = hi * 8;
    const int bid = blockIdx.x;
    const int g = bid & 7;                    // kv head
    const int p = (bid >> 3) & 31;            // pair index: qtiles p and 63-p
    const int s = bid >> 8;                   // chunk 0 or 1
    const int h = g * 4 + w;

    const int s0a = p * 32, s0b = (63 - p) * 32;
    const int nta = (s0a + 95) >> 6;          // 1..16
    // tile stream: s==0: qa tiles [0,nta) ++ qb tiles [0, 17-nta)   (17 tiles)
    //              s==1: qb tiles [17-nta, 33-nta)                  (16 tiles)
    const int nA  = s ? 0 : nta;
    const int bLo = s ? (17 - nta) : 0;
    const int nB  = s ? 16 : (17 - nta);
    const int nT  = nA + nB;

    const float C1 = 0.18033688011112042f;    // 0.125 * log2(e)
    const float C2 = 12.262908856239697f;     // 8.5  * log2(e)

    unsigned short* Oh = Op + (size_t)s * S_LEN * DOUT;
    float* Lh = Lp + (size_t)s * S_LEN * NH;

    int s0 = nA ? s0a : s0b;

    // Q fragments (B-operand layout): lane holds Q[s0+sl][16*ksq + 8*hi + j]
    short8v qf[4];
#pragma unroll
    for (int ksq = 0; ksq < 4; ksq++)
        qf[ksq] = *(const short8v*)(qb + (size_t)(s0 + sl) * QKVN + h * HD +
                                    ksq * 16 + hi8);

    float16v O[2];
#pragma unroll
    for (int df = 0; df < 2; df++)
#pragma unroll
        for (int r = 0; r < 16; r++) O[df][r] = 0.f;
    float lsum = 0.f;

    // staging addresses (unchanged from v4)
    const int kkey = tid >> 2, kch = tid & 3;     // K: 4 threads/key, 16 shorts
    const unsigned short* kg = kb + (size_t)kkey * QKVN + g * HD + kch * 16;
    const int vkey = tid & 63, vdb = tid >> 6;    // V: 1 thread/key, 16 dims
    const unsigned short* vg = vb + (size_t)vkey * QKVN + g * HD + vdb * 16;

    // per-wave epilogue: partial l + partial O (fp16) for one qtile
    auto epi = [&](int sbase) {
        float lt = lsum + __shfl_xor(lsum, 32);
        if (hi == 0) Lh[(size_t)(sbase + sl) * NH + h] = lt;
#pragma unroll
        for (int df = 0; df < 2; df++)
#pragma unroll
            for (int r = 0; r < 16; r++) {
                const int row = sbase + (r & 3) + 8 * (r >> 2) + 4 * hi;
                Oh[(size_t)row * DOUT + h * HD + df * 32 + sl] = f2h(O[df][r]);
            }
    };

    // preload first stream tile into regs
    const int it0 = nA ? 0 : bLo;
    const size_t p0 = (size_t)it0 * 64 * QKVN;
    ushort8v ka0 = *(const ushort8v*)(kg + p0);
    ushort8v ka1 = *(const ushort8v*)(kg + p0 + 8);
    ushort8v va0 = *(const ushort8v*)(vg + p0);
    ushort8v va1 = *(const ushort8v*)(vg + p0 + 8);

    for (int j = 0; j < nT; j++) {
        if (j > 0) __syncthreads();    // all reads of prev tile done
        {   // commit staged regs to LDS
            unsigned short* kd = Ks + kkey * KSTR + kch * 16;
            *(ushort8v*)kd = ka0;
            *(ushort8v*)(kd + 8) = ka1;
            unsigned short* vd = Vt + (size_t)(vdb * 16) * KSTR + vkey;
#pragma unroll
            for (int jj = 0; jj < 8; jj++) vd[jj * KSTR] = va0[jj];
#pragma unroll
            for (int jj = 0; jj < 8; jj++) vd[(8 + jj) * KSTR] = va1[jj];
        }
        __syncthreads();
        // prefetch next stream tile into regs
        if (j + 1 < nT) {
            const int itn = (j + 1 < nA) ? (j + 1) : (bLo + (j + 1 - nA));
            const size_t off = (size_t)itn * 64 * QKVN;
            ka0 = *(const ushort8v*)(kg + off);
            ka1 = *(const ushort8v*)(kg + off + 8);
            va0 = *(const ushort8v*)(vg + off);
            va1 = *(const ushort8v*)(vg + off + 8);
        }
        // qa -> qb segment boundary: flush qa partial, reset, switch Q
        if (nA && j == nA) {
            epi(s0a);
#pragma unroll
            for (int df = 0; df < 2; df++)
#pragma unroll
                for (int r = 0; r < 16; r++) O[df][r] = 0.f;
            lsum = 0.f;
            s0 = s0b;
#pragma unroll
            for (int ksq = 0; ksq < 4; ksq++)
                qf[ksq] = *(const short8v*)(qb + (size_t)(s0b + sl) * QKVN +
                                            h * HD + ksq * 16 + hi8);
        }

        const int it = (j < nA) ? j : (bLo + (j - nA));
        const int t0 = it * 64;
        const bool edge = (t0 + 63 > s0);

#pragma unroll
        for (int b = 0; b < 2; b++) {
            // K as A-operand: lane holds K[32b+sl][16*ksq + 8*hi + j]
            short8v kf[4];
#pragma unroll
            for (int ksq = 0; ksq < 4; ksq++)
                kf[ksq] = *(const short8v*)(Ks + (32 * b + sl) * KSTR +
                                            ksq * 16 + hi8);
            float16v sct;
#pragma unroll
            for (int r = 0; r < 16; r++) sct[r] = 0.f;
#pragma unroll
            for (int ksq = 0; ksq < 4; ksq++)
                sct = __builtin_amdgcn_mfma_f32_32x32x16_bf16(kf[ksq], qf[ksq],
                                                              sct, 0, 0, 0);
            // S^T element r: S[key = t0+32b+(r&3)+8*(r>>2)+4*hi][q = s0+sl]
            // fixed-max softmax: p = exp2(score*C1 - C2), fully lane-local
#pragma unroll
            for (int r = 0; r < 16; r++) {
                float arg = sct[r] * C1 - C2;
                if (edge) {
                    const int kglob = t0 + 32 * b + (r & 3) + 8 * (r >> 2) + 4 * hi;
                    arg = (kglob <= s0 + sl) ? arg : -100.f;
                }
                const float pv = exp2f(arg);
                sct[r] = pv;
                lsum += pv;
            }
            // pack to bf16 pairs: pk[i] = keys {8*(i>>1)+2*(i&1)+4*hi, +1}
            unsigned pk[8];
#pragma unroll
            for (int i = 0; i < 8; i++) pk[i] = cvtpk(sct[2 * i], sct[2 * i + 1]);
            // redistribute lane<->lane^32 into PV A-frags (keys 16ks+8hi+0..7)
#pragma unroll
            for (int kk = 0; kk < 2; kk++) {
                const unsigned x0 = pk[4 * kk + 0], x1 = pk[4 * kk + 1];
                const unsigned y0 = pk[4 * kk + 2], y1 = pk[4 * kk + 3];
                const unsigned a0 = __shfl_xor(x0, 32), a1 = __shfl_xor(x1, 32);
                const unsigned b0 = __shfl_xor(y0, 32), b1 = __shfl_xor(y1, 32);
                union { unsigned u[4]; short8v v; } pa;
                pa.u[0] = hi ? b0 : x0;
                pa.u[1] = hi ? b1 : x1;
                pa.u[2] = hi ? y0 : a0;
                pa.u[3] = hi ? y1 : a1;
                const int ks = 2 * b + kk;
#pragma unroll
                for (int df = 0; df < 2; df++) {
                    const short8v vf = *(const short8v*)(Vt + (size_t)(df * 32 + sl) * KSTR +
                                                         ks * 16 + hi8);
                    O[df] = __builtin_amdgcn_mfma_f32_32x32x16_bf16(pa.v, vf,
                                                                    O[df], 0, 0, 0);
                }
            }
        }
    }

    epi(s0);   // final segment (qb; or the only segment for s==1 blocks)
}

// ---------------------------------------------------------------------------
// Combine: rows < 1024 (qtiles 0..31) live entirely in partial 0;
// rows >= 1024 merge two partials. ctx bf16 written IN PLACE over O0.
// ---------------------------------------------------------------------------
__global__ __launch_bounds__(256) void combine(unsigned short* O01,   // aliased out
                                               const float* __restrict__ Lp) {
    const int i4 = (blockIdx.x * 256 + threadIdx.x) * 4;
    const int srow = i4 >> 11, hh = (i4 & 2047) >> 6;
    float l = Lp[(size_t)srow * NH + hh];
    ushort4v o0 = *(const ushort4v*)(O01 + i4);
    float acc[4];
#pragma unroll
    for (int j = 0; j < 4; j++) acc[j] = h2f(o0[j]);
    if (srow >= 1024) {      // wave-uniform per block (block spans 1024 elems)
        l += Lp[(size_t)S_LEN * NH + (size_t)srow * NH + hh];
        ushort4v o1 = *(const ushort4v*)(O01 + (size_t)S_LEN * DOUT + i4);
#pragma unroll
        for (int j = 0; j < 4; j++) acc[j] += h2f(o1[j]);
    }
    const float inv = 1.0f / l;
    ushort4v r;
#pragma unroll
    for (int j = 0; j < 4; j++) r[j] = f2bf(acc[j] * inv);
    *(ushort4v*)(O01 + i4) = r;
}

// ---------------------------------------------------------------------------
extern "C" void kernel_launch(void* const* d_in, const int* in_sizes, int n_in,
                              void* d_out, int out_size, void* d_ws, size_t ws_size,
                              hipStream_t stream) {
    const float* x    = (const float*)d_in[0];
    const float* cosb = (const float*)d_in[2];
    const float* sinb = (const float*)d_in[3];
    const float* Wq   = (const float*)d_in[4];
    const float* Wk   = (const float*)d_in[5];
    const float* Wv   = (const float*)d_in[6];
    const float* Wo   = (const float*)d_in[7];
    const float* qw   = (const float*)d_in[8];
    const float* kw   = (const float*)d_in[9];
    float* out = (float*)d_out;

    // ws layout (41.9 MB):
    //   W1  [0, 12.58M)      qkv weights^T bf16   -- dead after gemm_qkv
    //   XB  [12.58, 20.97M)  x bf16               -- dead after gemm_qkv
    //   WoT [20.97, 29.36M)  Wo^T bf16
    //   QKV [29.36, 41.94M)  q|k|v bf16
    // flash partials OVERLAY the dead W1+XB region:
    //   O0 [0, 8.39M) fp16 ; O1 [8.39, 16.78M) fp16 ; L0,L1 [16.78, 17.30M) fp32
    // combine writes ctx bf16 in place over O0; out-proj reads it from there.
    unsigned short* W1  = (unsigned short*)d_ws;
    unsigned short* XB  = W1 + (size_t)QKVN * DIN;
    unsigned short* WoT = XB + (size_t)S_LEN * DIN;
    unsigned short* QKV = WoT + (size_t)DIN * DOUT;
    unsigned short* Op  = (unsigned short*)d_ws;
    float*          Lp  = (float*)(Op + (size_t)2 * S_LEN * DOUT);
    unsigned short* CTX = Op;

    dim3 blk256(256);

    prep<<<dim3(14336), blk256, 0, stream>>>(Wq, Wk, Wv, Wo, x, W1, WoT, XB);

    gemm64<1><<<dim3(QKVN / 64, S_LEN / 128), blk256, 0, stream>>>(
        XB, W1, QKV, S_LEN, QKVN, DIN, qw, kw, cosb, sinb);

    // 512 uniform blocks: 8 kv-heads x 32 qtile-pairs x 2 chunks (17/16 tiles)
    flash_part<<<dim3(NKV * 32 * 2), blk256, 0, stream>>>(
        QKV, QKV + KOFF, QKV + VOFF, Op, Lp);

    combine<<<dim3(S_LEN * DOUT / 1024), blk256, 0, stream>>>(Op, Lp);

    gemm64<0><<<dim3(DIN / 64, S_LEN / 128), blk256, 0, stream>>>(
        CTX, WoT, out, S_LEN, DIN, DOUT, nullptr, nullptr, nullptr, nullptr);
}

// Round 2
// 236.638 us; speedup vs baseline: 1.1791x; 1.1190x over previous
//
#include <hip/hip_runtime.h>
#include <hip/hip_bf16.h>
#include <math.h>

#define S_LEN 2048
#define DIN   2048
#define NH    32
#define NKV   8
#define HD    64
#define DOUT  2048        // NH*HD
#define QKVN  3072        // DOUT + 2*KVD
#define KOFF  2048        // k col offset in qkv
#define VOFF  2560        // v col offset in qkv

typedef __attribute__((ext_vector_type(8))) short short8v;    // 8 bf16 (4 VGPRs)
typedef __attribute__((ext_vector_type(8))) unsigned short ushort8v;
typedef __attribute__((ext_vector_type(4))) unsigned short ushort4v;
typedef __attribute__((ext_vector_type(4))) float float4v;
typedef __attribute__((ext_vector_type(16))) float float16v;

__device__ __forceinline__ float bf2f(unsigned short u) {
    union { float f; unsigned u; } c; c.u = ((unsigned)u) << 16; return c.f;
}
__device__ __forceinline__ unsigned short f2bf(float f) {
    union { float f; unsigned u; } c; c.f = f;
    unsigned r = c.u + 0x7fffu + ((c.u >> 16) & 1u);   // RNE
    return (unsigned short)(r >> 16);
}
__device__ __forceinline__ unsigned short f2h(float f) {
    union { _Float16 h; unsigned short u; } c; c.h = (_Float16)f; return c.u;
}
__device__ __forceinline__ float h2f(unsigned short u) {
    union { _Float16 h; unsigned short u; } c; c.u = u; return (float)c.h;
}
__device__ __forceinline__ unsigned cvtpk(float lo, float hi) {
    unsigned r;
    asm("v_cvt_pk_bf16_f32 %0, %1, %2" : "=v"(r) : "v"(lo), "v"(hi));
    return r;
}

// ---------------------------------------------------------------------------
// Fused preprocessing, ONE launch, grid sections:
//   [0, 6144)        : Wq|Wk|Wv fp32 [K][N] -> bf16 [N][K] into W1 (32x32 tiles)
//   [6144, 10240)    : Wo transpose into WoT
//   [10240, 14336)   : x fp32 -> bf16 cast into XB
// ---------------------------------------------------------------------------
__global__ __launch_bounds__(256) void prep(const float* __restrict__ Wq,
                                            const float* __restrict__ Wk,
                                            const float* __restrict__ Wv,
                                            const float* __restrict__ Wo,
                                            const float* __restrict__ x,
                                            unsigned short* __restrict__ W1,
                                            unsigned short* __restrict__ WoT,
                                            unsigned short* __restrict__ XB) {
    __shared__ float t[32][33];
    const int a = blockIdx.x;
    const int tx = threadIdx.x & 31, ty = threadIdx.x >> 5;
    if (a < 6144) {                       // qkv weights: grid (96, 64)
        const int n0 = (a % 96) * 32, k0 = (a / 96) * 32;
        const float* src; int nn0, Nsrc;
        if (n0 < KOFF)      { src = Wq; nn0 = n0;        Nsrc = DOUT; }
        else if (n0 < VOFF) { src = Wk; nn0 = n0 - KOFF; Nsrc = 512; }
        else                { src = Wv; nn0 = n0 - VOFF; Nsrc = 512; }
#pragma unroll
        for (int j = ty; j < 32; j += 8)
            t[j][tx] = src[(size_t)(k0 + j) * Nsrc + nn0 + tx];
        __syncthreads();
#pragma unroll
        for (int j = ty; j < 32; j += 8)
            W1[(size_t)(n0 + j) * DIN + k0 + tx] = f2bf(t[tx][j]);
    } else if (a < 10240) {               // Wo: grid (64, 64), K=DOUT rows, N=DIN
        const int b = a - 6144;
        const int n0 = (b % 64) * 32, k0 = (b / 64) * 32;
#pragma unroll
        for (int j = ty; j < 32; j += 8)
            t[j][tx] = Wo[(size_t)(k0 + j) * DIN + n0 + tx];
        __syncthreads();
#pragma unroll
        for (int j = ty; j < 32; j += 8)
            WoT[(size_t)(n0 + j) * DOUT + k0 + tx] = f2bf(t[tx][j]);
    } else {                              // x cast: 4096 blocks x 1024 elems
        const int i = (a - 10240) * 1024 + threadIdx.x * 4;
        float4 v = *(const float4*)(x + i);
        XB[i + 0] = f2bf(v.x); XB[i + 1] = f2bf(v.y);
        XB[i + 2] = f2bf(v.z); XB[i + 3] = f2bf(v.w);
    }
}

// ---------------------------------------------------------------------------
// bf16 MFMA GEMM v2: 128x64 tile, BK=64, 4 waves stacked in M (wave = 32x64).
//   * Double-buffered LDS (48 KB -> 3 blocks/CU) + counted vmcnt: next tile's
//     6 global_load_lds issued BEFORE waiting; s_waitcnt vmcnt(6) + raw
//     s_barrier keeps the prefetch in flight across the barrier (T3/T4).
//     Trailing barrier preceded by lgkmcnt(0)+sched_barrier(0) so no wave
//     signals before its ds_reads pulled data (buffer about to be overwritten).
//   * T2 XOR swizzle, both-sides: gload_lds writes LDS linearly, so the
//     GLOBAL source chunk is pre-swizzled (lane loads chunk (lane&7)^(row&7))
//     and fragment ds_reads XOR the chunk with (row&7). Conflict-free b128.
//   * setprio(1) around the MFMA cluster (cross-block phase diversity).
// FUSE=1: bf16 out + per-head RMSNorm+RoPE epilogue (block col = one head).
// FUSE=0: fp32 out, plain.
// ---------------------------------------------------------------------------
template <int FUSE>
__global__ __launch_bounds__(256) void gemm64(const unsigned short* __restrict__ A,
                                              const unsigned short* __restrict__ Bt,
                                              void* __restrict__ Cv, int M, int N, int K,
                                              const float* __restrict__ qnw,
                                              const float* __restrict__ knw,
                                              const float* __restrict__ cosb,
                                              const float* __restrict__ sinb) {
    __shared__ __attribute__((aligned(16))) unsigned short As[2 * 128 * 64];
    __shared__ __attribute__((aligned(16))) unsigned short Bs[2 * 64 * 64];
    const int tid = threadIdx.x, lane = tid & 63, w = tid >> 6;
    const int bm = blockIdx.y * 128, bn = blockIdx.x * 64;
    const int wm = w * 32;

    float4v acc[2][4];
#pragma unroll
    for (int i = 0; i < 2; i++)
#pragma unroll
        for (int j = 0; j < 4; j++) acc[i][j] = (float4v){0.f, 0.f, 0.f, 0.f};

    // staging: lane covers row (lane>>3) of an 8-row group, 16B chunk (lane&7),
    // global source chunk pre-swizzled so linear LDS holds chunk^(row&7).
    const int srow = lane >> 3;
    const int schk = (lane & 7) ^ srow;
    const unsigned short* Ag[4];
    const unsigned short* Bg[2];
#pragma unroll
    for (int g = 0; g < 4; g++)
        Ag[g] = A + (size_t)(bm + w * 32 + g * 8 + srow) * K + schk * 8;
#pragma unroll
    for (int g = 0; g < 2; g++)
        Bg[g] = Bt + (size_t)(bn + w * 16 + g * 8 + srow) * K + schk * 8;

    auto STAGE = [&](int t, int b) {
        const size_t ko = (size_t)t * 64;
        unsigned short* Ad = As + b * (128 * 64) + (w * 32) * 64;
        unsigned short* Bd = Bs + b * (64 * 64) + (w * 16) * 64;
#pragma unroll
        for (int g = 0; g < 4; g++)
            __builtin_amdgcn_global_load_lds(
                (const __attribute__((address_space(1))) void*)(Ag[g] + ko),
                (__attribute__((address_space(3))) void*)(Ad + g * 8 * 64), 16, 0, 0);
#pragma unroll
        for (int g = 0; g < 2; g++)
            __builtin_amdgcn_global_load_lds(
                (const __attribute__((address_space(1))) void*)(Bg[g] + ko),
                (__attribute__((address_space(3))) void*)(Bd + g * 8 * 64), 16, 0, 0);
    };

    const int frow = lane & 15, quad = lane >> 4, sw = frow & 7;
    const int NT = K >> 6;

    STAGE(0, 0);                                   // prologue: tile 0 -> buf 0

    for (int t = 0; t < NT; t++) {
        const int c = t & 1;
        if (t + 1 < NT) {
            STAGE(t + 1, c ^ 1);
            asm volatile("s_waitcnt vmcnt(6)" ::: "memory");   // tile t done
        } else {
            asm volatile("s_waitcnt vmcnt(0)" ::: "memory");
        }
        __builtin_amdgcn_s_barrier();
        __builtin_amdgcn_sched_barrier(0);

        const unsigned short* Ab = As + c * (128 * 64);
        const unsigned short* Bb = Bs + c * (64 * 64);
        short8v af[2][2], bf[4][2];
#pragma unroll
        for (int fm = 0; fm < 2; fm++)
#pragma unroll
            for (int ks = 0; ks < 2; ks++)
                af[fm][ks] = *(const short8v*)(Ab + (wm + fm * 16 + frow) * 64 +
                                               (((ks * 4 + quad) ^ sw) * 8));
#pragma unroll
        for (int fn = 0; fn < 4; fn++)
#pragma unroll
            for (int ks = 0; ks < 2; ks++)
                bf[fn][ks] = *(const short8v*)(Bb + (fn * 16 + frow) * 64 +
                                               (((ks * 4 + quad) ^ sw) * 8));
        __builtin_amdgcn_s_setprio(1);
#pragma unroll
        for (int ks = 0; ks < 2; ks++)
#pragma unroll
            for (int fm = 0; fm < 2; fm++)
#pragma unroll
                for (int fn = 0; fn < 4; fn++)
                    acc[fm][fn] = __builtin_amdgcn_mfma_f32_16x16x32_bf16(
                        af[fm][ks], bf[fn][ks], acc[fm][fn], 0, 0, 0);
        __builtin_amdgcn_s_setprio(0);

        if (t + 1 < NT) {
            asm volatile("s_waitcnt lgkmcnt(0)" ::: "memory");  // reads pulled
            __builtin_amdgcn_sched_barrier(0);
            __builtin_amdgcn_s_barrier();          // buf c free to overwrite
        }
    }

    const int quad4 = lane >> 4, col16 = lane & 15;
    if constexpr (FUSE == 1) {
        unsigned short* C = (unsigned short*)Cv;
        const int head = bn >> 6;                 // one head per block col
        if (head < 40) {
            const float* nw = (head < 32) ? qnw : knw;
            float wv[4];
#pragma unroll
            for (int fn = 0; fn < 4; fn++) wv[fn] = nw[fn * 16 + col16];
#pragma unroll
            for (int fm = 0; fm < 2; fm++)
#pragma unroll
                for (int r = 0; r < 4; r++) {
                    float x0 = acc[fm][0][r], x1 = acc[fm][1][r];
                    float x2 = acc[fm][2][r], x3 = acc[fm][3][r];
                    float ss = x0 * x0 + x1 * x1 + x2 * x2 + x3 * x3;
                    ss += __shfl_xor(ss, 1); ss += __shfl_xor(ss, 2);
                    ss += __shfl_xor(ss, 4); ss += __shfl_xor(ss, 8);
                    const float inv = rsqrtf(ss * (1.0f / 64.0f) + 1e-6f);
                    float xn[4] = {x0 * inv * wv[0], x1 * inv * wv[1],
                                   x2 * inv * wv[2], x3 * inv * wv[3]};
                    const int row = bm + wm + fm * 16 + quad4 * 4 + r;
                    const float* cr = cosb + (size_t)row * HD;
                    const float* sr = sinb + (size_t)row * HD;
#pragma unroll
                    for (int fn = 0; fn < 4; fn++) {
                        const float rot = (fn < 2) ? -xn[fn + 2] : xn[fn - 2];
                        const float res = xn[fn] * cr[fn * 16 + col16] +
                                          rot * sr[fn * 16 + col16];
                        C[(size_t)row * N + bn + fn * 16 + col16] = f2bf(res);
                    }
                }
        } else {
#pragma unroll
            for (int fm = 0; fm < 2; fm++)
#pragma unroll
                for (int fn = 0; fn < 4; fn++)
#pragma unroll
                    for (int r = 0; r < 4; r++)
                        C[(size_t)(bm + wm + fm * 16 + quad4 * 4 + r) * N +
                          bn + fn * 16 + col16] = f2bf(acc[fm][fn][r]);
        }
    } else {
        float* C = (float*)Cv;
#pragma unroll
        for (int fm = 0; fm < 2; fm++)
#pragma unroll
            for (int fn = 0; fn < 4; fn++)
#pragma unroll
                for (int r = 0; r < 4; r++)
                    C[(size_t)(bm + wm + fm * 16 + quad4 * 4 + r) * N +
                      bn + fn * 16 + col16] = acc[fm][fn][r];
    }
}

// ---------------------------------------------------------------------------
// MFMA flash attention v5 (causal, GQA), fixed-max softmax.
//   * Swapped QK^T (mfma(K, Q), 32x32x16): S^T lands with q = lane&31, keys in
//     regs -> softmax fully lane-local; P packed to bf16 in-register via
//     v_cvt_pk_bf16_f32 and redistributed lane<->lane^32 with shfl_xor into
//     PV A-frags. NO P LDS round-trip.
//   * Causal load balance: block = (g, pair p, chunk s). qtile p is paired
//     with qtile 63-p: nt(p)+nt(63-p) == 33 for all p, chunked 17/16 ->
//     all 512 blocks have identical work, no straggler tail.
//   * qa (rows < 1024) is fully contained in chunk 0 -> single partial;
//     combine only merges two partials for rows >= 1024.
// LDS = 2 x 64 x KSTR shorts = 22.5 KB. 512 blocks, 2/CU, 8 waves/CU flat.
// ---------------------------------------------------------------------------
#define KSTR 88    // K/V LDS row stride (shorts)

__global__ __launch_bounds__(256) void flash_part(const unsigned short* __restrict__ qb,
                                                  const unsigned short* __restrict__ kb,
                                                  const unsigned short* __restrict__ vb,
                                                  unsigned short* __restrict__ Op,
                                                  float* __restrict__ Lp) {
    __shared__ __attribute__((aligned(16))) unsigned short Ks[64 * KSTR];
    __shared__ __attribute__((aligned(16))) unsigned short Vt[64 * KSTR];

    const int tid = threadIdx.x, lane = tid & 63, w = tid >> 6;
    const int sl = lane & 31, hi = lane >> 5, hi8 = hi * 8;
    const int bid = blockIdx.x;
    const int g = bid & 7;                    // kv head
    const int p = (bid >> 3) & 31;            // pair index: qtiles p and 63-p
    const int s = bid >> 8;                   // chunk 0 or 1
    const int h = g * 4 + w;

    const int s0a = p * 32, s0b = (63 - p) * 32;
    const int nta = (s0a + 95) >> 6;          // 1..16
    const int nA  = s ? 0 : nta;
    const int bLo = s ? (17 - nta) : 0;
    const int nB  = s ? 16 : (17 - nta);
    const int nT  = nA + nB;

    const float C1 = 0.18033688011112042f;    // 0.125 * log2(e)
    const float C2 = 12.262908856239697f;     // 8.5  * log2(e)

    unsigned short* Oh = Op + (size_t)s * S_LEN * DOUT;
    float* Lh = Lp + (size_t)s * S_LEN * NH;

    int s0 = nA ? s0a : s0b;

    // Q fragments (B-operand layout): lane holds Q[s0+sl][16*ksq + 8*hi + j]
    short8v qf[4];
#pragma unroll
    for (int ksq = 0; ksq < 4; ksq++)
        qf[ksq] = *(const short8v*)(qb + (size_t)(s0 + sl) * QKVN + h * HD +
                                    ksq * 16 + hi8);

    float16v O[2];
#pragma unroll
    for (int df = 0; df < 2; df++)
#pragma unroll
        for (int r = 0; r < 16; r++) O[df][r] = 0.f;
    float lsum = 0.f;

    const int kkey = tid >> 2, kch = tid & 3;     // K: 4 threads/key, 16 shorts
    const unsigned short* kg = kb + (size_t)kkey * QKVN + g * HD + kch * 16;
    const int vkey = tid & 63, vdb = tid >> 6;    // V: 1 thread/key, 16 dims
    const unsigned short* vg = vb + (size_t)vkey * QKVN + g * HD + vdb * 16;

    auto epi = [&](int sbase) {
        float lt = lsum + __shfl_xor(lsum, 32);
        if (hi == 0) Lh[(size_t)(sbase + sl) * NH + h] = lt;
#pragma unroll
        for (int df = 0; df < 2; df++)
#pragma unroll
            for (int r = 0; r < 16; r++) {
                const int row = sbase + (r & 3) + 8 * (r >> 2) + 4 * hi;
                Oh[(size_t)row * DOUT + h * HD + df * 32 + sl] = f2h(O[df][r]);
            }
    };

    const int it0 = nA ? 0 : bLo;
    const size_t p0 = (size_t)it0 * 64 * QKVN;
    ushort8v ka0 = *(const ushort8v*)(kg + p0);
    ushort8v ka1 = *(const ushort8v*)(kg + p0 + 8);
    ushort8v va0 = *(const ushort8v*)(vg + p0);
    ushort8v va1 = *(const ushort8v*)(vg + p0 + 8);

    for (int j = 0; j < nT; j++) {
        if (j > 0) __syncthreads();    // all reads of prev tile done
        {   // commit staged regs to LDS
            unsigned short* kd = Ks + kkey * KSTR + kch * 16;
            *(ushort8v*)kd = ka0;
            *(ushort8v*)(kd + 8) = ka1;
            unsigned short* vd = Vt + (size_t)(vdb * 16) * KSTR + vkey;
#pragma unroll
            for (int jj = 0; jj < 8; jj++) vd[jj * KSTR] = va0[jj];
#pragma unroll
            for (int jj = 0; jj < 8; jj++) vd[(8 + jj) * KSTR] = va1[jj];
        }
        __syncthreads();
        if (j + 1 < nT) {
            const int itn = (j + 1 < nA) ? (j + 1) : (bLo + (j + 1 - nA));
            const size_t off = (size_t)itn * 64 * QKVN;
            ka0 = *(const ushort8v*)(kg + off);
            ka1 = *(const ushort8v*)(kg + off + 8);
            va0 = *(const ushort8v*)(vg + off);
            va1 = *(const ushort8v*)(vg + off + 8);
        }
        if (nA && j == nA) {           // qa -> qb boundary: flush, reset, reload Q
            epi(s0a);
#pragma unroll
            for (int df = 0; df < 2; df++)
#pragma unroll
                for (int r = 0; r < 16; r++) O[df][r] = 0.f;
            lsum = 0.f;
            s0 = s0b;
#pragma unroll
            for (int ksq = 0; ksq < 4; ksq++)
                qf[ksq] = *(const short8v*)(qb + (size_t)(s0b + sl) * QKVN +
                                            h * HD + ksq * 16 + hi8);
        }

        const int it = (j < nA) ? j : (bLo + (j - nA));
        const int t0 = it * 64;
        const bool edge = (t0 + 63 > s0);

#pragma unroll
        for (int b = 0; b < 2; b++) {
            short8v kf[4];
#pragma unroll
            for (int ksq = 0; ksq < 4; ksq++)
                kf[ksq] = *(const short8v*)(Ks + (32 * b + sl) * KSTR +
                                            ksq * 16 + hi8);
            float16v sct;
#pragma unroll
            for (int r = 0; r < 16; r++) sct[r] = 0.f;
#pragma unroll
            for (int ksq = 0; ksq < 4; ksq++)
                sct = __builtin_amdgcn_mfma_f32_32x32x16_bf16(kf[ksq], qf[ksq],
                                                              sct, 0, 0, 0);
#pragma unroll
            for (int r = 0; r < 16; r++) {
                float arg = sct[r] * C1 - C2;
                if (edge) {
                    const int kglob = t0 + 32 * b + (r & 3) + 8 * (r >> 2) + 4 * hi;
                    arg = (kglob <= s0 + sl) ? arg : -100.f;
                }
                const float pv = exp2f(arg);
                sct[r] = pv;
                lsum += pv;
            }
            unsigned pk[8];
#pragma unroll
            for (int i = 0; i < 8; i++) pk[i] = cvtpk(sct[2 * i], sct[2 * i + 1]);
#pragma unroll
            for (int kk = 0; kk < 2; kk++) {
                const unsigned x0 = pk[4 * kk + 0], x1 = pk[4 * kk + 1];
                const unsigned y0 = pk[4 * kk + 2], y1 = pk[4 * kk + 3];
                const unsigned a0 = __shfl_xor(x0, 32), a1 = __shfl_xor(x1, 32);
                const unsigned b0 = __shfl_xor(y0, 32), b1 = __shfl_xor(y1, 32);
                union { unsigned u[4]; short8v v; } pa;
                pa.u[0] = hi ? b0 : x0;
                pa.u[1] = hi ? b1 : x1;
                pa.u[2] = hi ? y0 : a0;
                pa.u[3] = hi ? y1 : a1;
                const int ks = 2 * b + kk;
#pragma unroll
                for (int df = 0; df < 2; df++) {
                    const short8v vf = *(const short8v*)(Vt + (size_t)(df * 32 + sl) * KSTR +
                                                         ks * 16 + hi8);
                    O[df] = __builtin_amdgcn_mfma_f32_32x32x16_bf16(pa.v, vf,
                                                                    O[df], 0, 0, 0);
                }
            }
        }
    }

    epi(s0);   // final segment (qb; or the only segment for s==1 blocks)
}

// ---------------------------------------------------------------------------
// Combine: rows < 1024 (qtiles 0..31) live entirely in partial 0;
// rows >= 1024 merge two partials. ctx bf16 written IN PLACE over O0.
// ---------------------------------------------------------------------------
__global__ __launch_bounds__(256) void combine(unsigned short* O01,   // aliased out
                                               const float* __restrict__ Lp) {
    const int i4 = (blockIdx.x * 256 + threadIdx.x) * 4;
    const int srow = i4 >> 11, hh = (i4 & 2047) >> 6;
    float l = Lp[(size_t)srow * NH + hh];
    ushort4v o0 = *(const ushort4v*)(O01 + i4);
    float acc[4];
#pragma unroll
    for (int j = 0; j < 4; j++) acc[j] = h2f(o0[j]);
    if (srow >= 1024) {      // wave-uniform per block (block spans 1024 elems)
        l += Lp[(size_t)S_LEN * NH + (size_t)srow * NH + hh];
        ushort4v o1 = *(const ushort4v*)(O01 + (size_t)S_LEN * DOUT + i4);
#pragma unroll
        for (int j = 0; j < 4; j++) acc[j] += h2f(o1[j]);
    }
    const float inv = 1.0f / l;
    ushort4v r;
#pragma unroll
    for (int j = 0; j < 4; j++) r[j] = f2bf(acc[j] * inv);
    *(ushort4v*)(O01 + i4) = r;
}

// ---------------------------------------------------------------------------
extern "C" void kernel_launch(void* const* d_in, const int* in_sizes, int n_in,
                              void* d_out, int out_size, void* d_ws, size_t ws_size,
                              hipStream_t stream) {
    const float* x    = (const float*)d_in[0];
    const float* cosb = (const float*)d_in[2];
    const float* sinb = (const float*)d_in[3];
    const float* Wq   = (const float*)d_in[4];
    const float* Wk   = (const float*)d_in[5];
    const float* Wv   = (const float*)d_in[6];
    const float* Wo   = (const float*)d_in[7];
    const float* qw   = (const float*)d_in[8];
    const float* kw   = (const float*)d_in[9];
    float* out = (float*)d_out;

    // ws layout (41.9 MB):
    //   W1  [0, 12.58M)      qkv weights^T bf16   -- dead after gemm_qkv
    //   XB  [12.58, 20.97M)  x bf16               -- dead after gemm_qkv
    //   WoT [20.97, 29.36M)  Wo^T bf16
    //   QKV [29.36, 41.94M)  q|k|v bf16
    // flash partials OVERLAY the dead W1+XB region:
    //   O0 [0, 8.39M) fp16 ; O1 [8.39, 16.78M) fp16 ; L0,L1 [16.78, 17.30M) fp32
    // combine writes ctx bf16 in place over O0; out-proj reads it from there.
    unsigned short* W1  = (unsigned short*)d_ws;
    unsigned short* XB  = W1 + (size_t)QKVN * DIN;
    unsigned short* WoT = XB + (size_t)S_LEN * DIN;
    unsigned short* QKV = WoT + (size_t)DIN * DOUT;
    unsigned short* Op  = (unsigned short*)d_ws;
    float*          Lp  = (float*)(Op + (size_t)2 * S_LEN * DOUT);
    unsigned short* CTX = Op;

    dim3 blk256(256);

    prep<<<dim3(14336), blk256, 0, stream>>>(Wq, Wk, Wv, Wo, x, W1, WoT, XB);

    gemm64<1><<<dim3(QKVN / 64, S_LEN / 128), blk256, 0, stream>>>(
        XB, W1, QKV, S_LEN, QKVN, DIN, qw, kw, cosb, sinb);

    // 512 uniform blocks: 8 kv-heads x 32 qtile-pairs x 2 chunks (17/16 tiles)
    flash_part<<<dim3(NKV * 32 * 2), blk256, 0, stream>>>(
        QKV, QKV + KOFF, QKV + VOFF, Op, Lp);

    combine<<<dim3(S_LEN * DOUT / 1024), blk256, 0, stream>>>(Op, Lp);

    gemm64<0><<<dim3(DIN / 64, S_LEN / 128), blk256, 0, stream>>>(
        CTX, WoT, out, S_LEN, DIN, DOUT, nullptr, nullptr, nullptr, nullptr);
}

// Round 3
// 236.561 us; speedup vs baseline: 1.1795x; 1.0003x over previous
//
#include <hip/hip_runtime.h>
#include <hip/hip_bf16.h>
#include <math.h>

#define S_LEN 2048
#define DIN   2048
#define NH    32
#define NKV   8
#define HD    64
#define DOUT  2048        // NH*HD
#define QKVN  3072        // DOUT + 2*KVD
#define KOFF  2048        // k col offset in qkv
#define VOFF  2560        // v col offset in qkv

typedef __attribute__((ext_vector_type(8))) short short8v;    // 8 bf16 (4 VGPRs)
typedef __attribute__((ext_vector_type(8))) unsigned short ushort8v;
typedef __attribute__((ext_vector_type(4))) unsigned short ushort4v;
typedef __attribute__((ext_vector_type(4))) float float4v;
typedef __attribute__((ext_vector_type(16))) float float16v;

__device__ __forceinline__ float bf2f(unsigned short u) {
    union { float f; unsigned u; } c; c.u = ((unsigned)u) << 16; return c.f;
}
__device__ __forceinline__ unsigned short f2bf(float f) {
    union { float f; unsigned u; } c; c.f = f;
    unsigned r = c.u + 0x7fffu + ((c.u >> 16) & 1u);   // RNE
    return (unsigned short)(r >> 16);
}
__device__ __forceinline__ unsigned short f2h(float f) {
    union { _Float16 h; unsigned short u; } c; c.h = (_Float16)f; return c.u;
}
__device__ __forceinline__ float h2f(unsigned short u) {
    union { _Float16 h; unsigned short u; } c; c.u = u; return (float)c.h;
}
__device__ __forceinline__ unsigned cvtpk(float lo, float hi) {
    unsigned r;
    asm("v_cvt_pk_bf16_f32 %0, %1, %2" : "=v"(r) : "v"(lo), "v"(hi));
    return r;
}

// ---------------------------------------------------------------------------
// Fused preprocessing, ONE launch, grid sections:
//   [0, 6144)        : Wq|Wk|Wv fp32 [K][N] -> bf16 [N][K] into W1 (32x32 tiles)
//   [6144, 10240)    : Wo transpose into WoT
//   [10240, 14336)   : x fp32 -> bf16 cast into XB
// ---------------------------------------------------------------------------
__global__ __launch_bounds__(256) void prep(const float* __restrict__ Wq,
                                            const float* __restrict__ Wk,
                                            const float* __restrict__ Wv,
                                            const float* __restrict__ Wo,
                                            const float* __restrict__ x,
                                            unsigned short* __restrict__ W1,
                                            unsigned short* __restrict__ WoT,
                                            unsigned short* __restrict__ XB) {
    __shared__ float t[32][33];
    const int a = blockIdx.x;
    const int tx = threadIdx.x & 31, ty = threadIdx.x >> 5;
    if (a < 6144) {                       // qkv weights: grid (96, 64)
        const int n0 = (a % 96) * 32, k0 = (a / 96) * 32;
        const float* src; int nn0, Nsrc;
        if (n0 < KOFF)      { src = Wq; nn0 = n0;        Nsrc = DOUT; }
        else if (n0 < VOFF) { src = Wk; nn0 = n0 - KOFF; Nsrc = 512; }
        else                { src = Wv; nn0 = n0 - VOFF; Nsrc = 512; }
#pragma unroll
        for (int j = ty; j < 32; j += 8)
            t[j][tx] = src[(size_t)(k0 + j) * Nsrc + nn0 + tx];
        __syncthreads();
#pragma unroll
        for (int j = ty; j < 32; j += 8)
            W1[(size_t)(n0 + j) * DIN + k0 + tx] = f2bf(t[tx][j]);
    } else if (a < 10240) {               // Wo: grid (64, 64), K=DOUT rows, N=DIN
        const int b = a - 6144;
        const int n0 = (b % 64) * 32, k0 = (b / 64) * 32;
#pragma unroll
        for (int j = ty; j < 32; j += 8)
            t[j][tx] = Wo[(size_t)(k0 + j) * DIN + n0 + tx];
        __syncthreads();
#pragma unroll
        for (int j = ty; j < 32; j += 8)
            WoT[(size_t)(n0 + j) * DOUT + k0 + tx] = f2bf(t[tx][j]);
    } else {                              // x cast: 4096 blocks x 1024 elems
        const int i = (a - 10240) * 1024 + threadIdx.x * 4;
        float4 v = *(const float4*)(x + i);
        XB[i + 0] = f2bf(v.x); XB[i + 1] = f2bf(v.y);
        XB[i + 2] = f2bf(v.z); XB[i + 3] = f2bf(v.w);
    }
}

// ---------------------------------------------------------------------------
// bf16 MFMA GEMM v2: 128x64 tile, BK=64, 4 waves stacked in M (wave = 32x64).
//   * Double-buffered LDS + counted vmcnt (T3/T4): prefetch in flight across
//     the barrier. T2 XOR swizzle via pre-swizzled global source. setprio(1)
//     around MFMA cluster.
// FUSE=1: bf16 out + per-head RMSNorm+RoPE epilogue (block col = one head).
// FUSE=0: fp32 out, plain.
// ---------------------------------------------------------------------------
template <int FUSE>
__global__ __launch_bounds__(256) void gemm64(const unsigned short* __restrict__ A,
                                              const unsigned short* __restrict__ Bt,
                                              void* __restrict__ Cv, int M, int N, int K,
                                              const float* __restrict__ qnw,
                                              const float* __restrict__ knw,
                                              const float* __restrict__ cosb,
                                              const float* __restrict__ sinb) {
    __shared__ __attribute__((aligned(16))) unsigned short As[2 * 128 * 64];
    __shared__ __attribute__((aligned(16))) unsigned short Bs[2 * 64 * 64];
    const int tid = threadIdx.x, lane = tid & 63, w = tid >> 6;
    const int bm = blockIdx.y * 128, bn = blockIdx.x * 64;
    const int wm = w * 32;

    float4v acc[2][4];
#pragma unroll
    for (int i = 0; i < 2; i++)
#pragma unroll
        for (int j = 0; j < 4; j++) acc[i][j] = (float4v){0.f, 0.f, 0.f, 0.f};

    const int srow = lane >> 3;
    const int schk = (lane & 7) ^ srow;
    const unsigned short* Ag[4];
    const unsigned short* Bg[2];
#pragma unroll
    for (int g = 0; g < 4; g++)
        Ag[g] = A + (size_t)(bm + w * 32 + g * 8 + srow) * K + schk * 8;
#pragma unroll
    for (int g = 0; g < 2; g++)
        Bg[g] = Bt + (size_t)(bn + w * 16 + g * 8 + srow) * K + schk * 8;

    auto STAGE = [&](int t, int b) {
        const size_t ko = (size_t)t * 64;
        unsigned short* Ad = As + b * (128 * 64) + (w * 32) * 64;
        unsigned short* Bd = Bs + b * (64 * 64) + (w * 16) * 64;
#pragma unroll
        for (int g = 0; g < 4; g++)
            __builtin_amdgcn_global_load_lds(
                (const __attribute__((address_space(1))) void*)(Ag[g] + ko),
                (__attribute__((address_space(3))) void*)(Ad + g * 8 * 64), 16, 0, 0);
#pragma unroll
        for (int g = 0; g < 2; g++)
            __builtin_amdgcn_global_load_lds(
                (const __attribute__((address_space(1))) void*)(Bg[g] + ko),
                (__attribute__((address_space(3))) void*)(Bd + g * 8 * 64), 16, 0, 0);
    };

    const int frow = lane & 15, quad = lane >> 4, sw = frow & 7;
    const int NT = K >> 6;

    STAGE(0, 0);                                   // prologue: tile 0 -> buf 0

    for (int t = 0; t < NT; t++) {
        const int c = t & 1;
        if (t + 1 < NT) {
            STAGE(t + 1, c ^ 1);
            asm volatile("s_waitcnt vmcnt(6)" ::: "memory");   // tile t done
        } else {
            asm volatile("s_waitcnt vmcnt(0)" ::: "memory");
        }
        __builtin_amdgcn_s_barrier();
        __builtin_amdgcn_sched_barrier(0);

        const unsigned short* Ab = As + c * (128 * 64);
        const unsigned short* Bb = Bs + c * (64 * 64);
        short8v af[2][2], bf[4][2];
#pragma unroll
        for (int fm = 0; fm < 2; fm++)
#pragma unroll
            for (int ks = 0; ks < 2; ks++)
                af[fm][ks] = *(const short8v*)(Ab + (wm + fm * 16 + frow) * 64 +
                                               (((ks * 4 + quad) ^ sw) * 8));
#pragma unroll
        for (int fn = 0; fn < 4; fn++)
#pragma unroll
            for (int ks = 0; ks < 2; ks++)
                bf[fn][ks] = *(const short8v*)(Bb + (fn * 16 + frow) * 64 +
                                               (((ks * 4 + quad) ^ sw) * 8));
        __builtin_amdgcn_s_setprio(1);
#pragma unroll
        for (int ks = 0; ks < 2; ks++)
#pragma unroll
            for (int fm = 0; fm < 2; fm++)
#pragma unroll
                for (int fn = 0; fn < 4; fn++)
                    acc[fm][fn] = __builtin_amdgcn_mfma_f32_16x16x32_bf16(
                        af[fm][ks], bf[fn][ks], acc[fm][fn], 0, 0, 0);
        __builtin_amdgcn_s_setprio(0);

        if (t + 1 < NT) {
            asm volatile("s_waitcnt lgkmcnt(0)" ::: "memory");  // reads pulled
            __builtin_amdgcn_sched_barrier(0);
            __builtin_amdgcn_s_barrier();          // buf c free to overwrite
        }
    }

    const int quad4 = lane >> 4, col16 = lane & 15;
    if constexpr (FUSE == 1) {
        unsigned short* C = (unsigned short*)Cv;
        const int head = bn >> 6;                 // one head per block col
        if (head < 40) {
            const float* nw = (head < 32) ? qnw : knw;
            float wv[4];
#pragma unroll
            for (int fn = 0; fn < 4; fn++) wv[fn] = nw[fn * 16 + col16];
#pragma unroll
            for (int fm = 0; fm < 2; fm++)
#pragma unroll
                for (int r = 0; r < 4; r++) {
                    float x0 = acc[fm][0][r], x1 = acc[fm][1][r];
                    float x2 = acc[fm][2][r], x3 = acc[fm][3][r];
                    float ss = x0 * x0 + x1 * x1 + x2 * x2 + x3 * x3;
                    ss += __shfl_xor(ss, 1); ss += __shfl_xor(ss, 2);
                    ss += __shfl_xor(ss, 4); ss += __shfl_xor(ss, 8);
                    const float inv = rsqrtf(ss * (1.0f / 64.0f) + 1e-6f);
                    float xn[4] = {x0 * inv * wv[0], x1 * inv * wv[1],
                                   x2 * inv * wv[2], x3 * inv * wv[3]};
                    const int row = bm + wm + fm * 16 + quad4 * 4 + r;
                    const float* cr = cosb + (size_t)row * HD;
                    const float* sr = sinb + (size_t)row * HD;
#pragma unroll
                    for (int fn = 0; fn < 4; fn++) {
                        const float rot = (fn < 2) ? -xn[fn + 2] : xn[fn - 2];
                        const float res = xn[fn] * cr[fn * 16 + col16] +
                                          rot * sr[fn * 16 + col16];
                        C[(size_t)row * N + bn + fn * 16 + col16] = f2bf(res);
                    }
                }
        } else {
#pragma unroll
            for (int fm = 0; fm < 2; fm++)
#pragma unroll
                for (int fn = 0; fn < 4; fn++)
#pragma unroll
                    for (int r = 0; r < 4; r++)
                        C[(size_t)(bm + wm + fm * 16 + quad4 * 4 + r) * N +
                          bn + fn * 16 + col16] = f2bf(acc[fm][fn][r]);
        }
    } else {
        float* C = (float*)Cv;
#pragma unroll
        for (int fm = 0; fm < 2; fm++)
#pragma unroll
            for (int fn = 0; fn < 4; fn++)
#pragma unroll
                for (int r = 0; r < 4; r++)
                    C[(size_t)(bm + wm + fm * 16 + quad4 * 4 + r) * N +
                      bn + fn * 16 + col16] = acc[fm][fn][r];
    }
}

// ---------------------------------------------------------------------------
// MFMA flash attention v6 (causal, GQA), fixed-max softmax.
//   * Swapped QK^T (mfma(K, Q), 32x32x16), lane-local softmax, in-register
//     P->bf16 (cvt_pk) + shfl_xor(32) redistribution. No P LDS round-trip.
//   * v6: double-buffered K/V LDS (44 KB), ONE barrier per tile. Per iter:
//     barrier -> frag reads buf[cur] -> commit regs(t+1)->buf[cur^1] ->
//     issue global loads(t+2) -> compute. Commit drains under compute;
//     prefetch distance 2 tiles; barrier count halved.
//   * V commit: 8 v_perm_b32 pack key-pairs -> 8 ds_write_b32 (was 16 b16).
//   * qfB (second segment Q) preloaded at start; boundary = 16 v_movs.
//   * Causal balance: qtile p paired with 63-p (33 tiles), 2 chunks 17/16;
//     512 uniform blocks, 2 partials, combine merges rows >= 1024.
// ---------------------------------------------------------------------------
#define KSTR 88    // K/V LDS row stride (shorts)

__global__ __launch_bounds__(256) void flash_part(const unsigned short* __restrict__ qb,
                                                  const unsigned short* __restrict__ kb,
                                                  const unsigned short* __restrict__ vb,
                                                  unsigned short* __restrict__ Op,
                                                  float* __restrict__ Lp) {
    __shared__ __attribute__((aligned(16))) unsigned short Ks[2][64 * KSTR];
    __shared__ __attribute__((aligned(16))) unsigned short Vt[2][64 * KSTR];

    const int tid = threadIdx.x, lane = tid & 63, w = tid >> 6;
    const int sl = lane & 31, hi = lane >> 5, hi8 = hi * 8;
    const int bid = blockIdx.x;
    const int g = bid & 7;                    // kv head
    const int p = (bid >> 3) & 31;            // pair index: qtiles p and 63-p
    const int s = bid >> 8;                   // chunk 0 or 1
    const int h = g * 4 + w;

    const int s0a = p * 32, s0b = (63 - p) * 32;
    const int nta = (s0a + 95) >> 6;          // 1..16
    const int nA  = s ? 0 : nta;
    const int bLo = s ? (17 - nta) : 0;
    const int nB  = s ? 16 : (17 - nta);
    const int nT  = nA + nB;

    const float C1 = 0.18033688011112042f;    // 0.125 * log2(e)
    const float C2 = 12.262908856239697f;     // 8.5  * log2(e)

    unsigned short* Oh = Op + (size_t)s * S_LEN * DOUT;
    float* Lh = Lp + (size_t)s * S_LEN * NH;

    int s0 = nA ? s0a : s0b;

    // Q fragments (B-operand layout): lane holds Q[s0+sl][16*ksq + 8*hi + j]
    short8v qf[4], qfB[4];
#pragma unroll
    for (int ksq = 0; ksq < 4; ksq++)
        qf[ksq] = *(const short8v*)(qb + (size_t)(s0 + sl) * QKVN + h * HD +
                                    ksq * 16 + hi8);
    if (nA) {
#pragma unroll
        for (int ksq = 0; ksq < 4; ksq++)
            qfB[ksq] = *(const short8v*)(qb + (size_t)(s0b + sl) * QKVN + h * HD +
                                         ksq * 16 + hi8);
    }

    float16v O[2];
#pragma unroll
    for (int df = 0; df < 2; df++)
#pragma unroll
        for (int r = 0; r < 16; r++) O[df][r] = 0.f;
    float lsum = 0.f;

    // staging addresses
    const int kkey = tid >> 2, kch = tid & 3;     // K: 4 threads/key, 16 shorts
    const unsigned short* kg = kb + (size_t)kkey * QKVN + g * HD + kch * 16;
    const int kp = tid & 31, vdbb = tid >> 5;     // V: keys 2kp,2kp+1; dims vdbb*8..+8
    const unsigned short* vg0 = vb + (size_t)(2 * kp) * QKVN + g * HD + vdbb * 8;
    const unsigned short* vg1 = vg0 + QKVN;

    auto epi = [&](int sbase) {
        float lt = lsum + __shfl_xor(lsum, 32);
        if (hi == 0) Lh[(size_t)(sbase + sl) * NH + h] = lt;
#pragma unroll
        for (int df = 0; df < 2; df++)
#pragma unroll
            for (int r = 0; r < 16; r++) {
                const int row = sbase + (r & 3) + 8 * (r >> 2) + 4 * hi;
                Oh[(size_t)row * DOUT + h * HD + df * 32 + sl] = f2h(O[df][r]);
            }
    };

    auto tileIdx = [&](int j) { return (j < nA) ? j : (bLo + (j - nA)); };

    ushort8v ka0, ka1, va0, va1;
    auto LOADREGS = [&](int it) {
        const size_t off = (size_t)it * 64 * QKVN;
        ka0 = *(const ushort8v*)(kg + off);
        ka1 = *(const ushort8v*)(kg + off + 8);
        va0 = *(const ushort8v*)(vg0 + off);
        va1 = *(const ushort8v*)(vg1 + off);
    };
    auto COMMIT = [&](int b) {
        unsigned short* kd = Ks[b] + kkey * KSTR + kch * 16;
        *(ushort8v*)kd = ka0;
        *(ushort8v*)(kd + 8) = ka1;
        // V: pack key-pair per dim -> 8 x b32, banks 0..31 across lanes
        union { ushort8v v; unsigned d[4]; } ua, ub;
        ua.v = va0; ub.v = va1;
        unsigned short* vd = Vt[b] + (size_t)(vdbb * 8) * KSTR + 2 * kp;
#pragma unroll
        for (int i = 0; i < 8; i++) {
            const unsigned sel = (i & 1) ? 0x07060302u : 0x05040100u;
            const unsigned word = __builtin_amdgcn_perm(ub.d[i >> 1], ua.d[i >> 1], sel);
            *(unsigned*)(vd + (size_t)i * KSTR) = word;
        }
    };

    // prologue: tile0 -> regs -> buf0; tile1 -> regs
    LOADREGS(tileIdx(0));
    COMMIT(0);
    if (nT > 1) LOADREGS(tileIdx(1));

    for (int j = 0; j < nT; j++) {
        const int cur = j & 1;
        __syncthreads();                    // buf[cur] committed; prev reads done
        if (j + 1 < nT) COMMIT(cur ^ 1);    // regs hold tile j+1
        if (j + 2 < nT) LOADREGS(tileIdx(j + 2));
        if (nA && j == nA) {                // qa -> qb boundary
            epi(s0a);
#pragma unroll
            for (int df = 0; df < 2; df++)
#pragma unroll
                for (int r = 0; r < 16; r++) O[df][r] = 0.f;
            lsum = 0.f;
            s0 = s0b;
#pragma unroll
            for (int ksq = 0; ksq < 4; ksq++) qf[ksq] = qfB[ksq];
        }

        const int t0 = tileIdx(j) * 64;
        const bool edge = (t0 + 63 > s0);

#pragma unroll
        for (int b = 0; b < 2; b++) {
            short8v kf[4];
#pragma unroll
            for (int ksq = 0; ksq < 4; ksq++)
                kf[ksq] = *(const short8v*)(Ks[cur] + (32 * b + sl) * KSTR +
                                            ksq * 16 + hi8);
            float16v sct;
#pragma unroll
            for (int r = 0; r < 16; r++) sct[r] = 0.f;
            __builtin_amdgcn_s_setprio(1);
#pragma unroll
            for (int ksq = 0; ksq < 4; ksq++)
                sct = __builtin_amdgcn_mfma_f32_32x32x16_bf16(kf[ksq], qf[ksq],
                                                              sct, 0, 0, 0);
            __builtin_amdgcn_s_setprio(0);
#pragma unroll
            for (int r = 0; r < 16; r++) {
                float arg = sct[r] * C1 - C2;
                if (edge) {
                    const int kglob = t0 + 32 * b + (r & 3) + 8 * (r >> 2) + 4 * hi;
                    arg = (kglob <= s0 + sl) ? arg : -100.f;
                }
                const float pv = exp2f(arg);
                sct[r] = pv;
                lsum += pv;
            }
            unsigned pk[8];
#pragma unroll
            for (int i = 0; i < 8; i++) pk[i] = cvtpk(sct[2 * i], sct[2 * i + 1]);
#pragma unroll
            for (int kk = 0; kk < 2; kk++) {
                const unsigned x0 = pk[4 * kk + 0], x1 = pk[4 * kk + 1];
                const unsigned y0 = pk[4 * kk + 2], y1 = pk[4 * kk + 3];
                const unsigned a0 = __shfl_xor(x0, 32), a1 = __shfl_xor(x1, 32);
                const unsigned b0 = __shfl_xor(y0, 32), b1 = __shfl_xor(y1, 32);
                union { unsigned u[4]; short8v v; } pa;
                pa.u[0] = hi ? b0 : x0;
                pa.u[1] = hi ? b1 : x1;
                pa.u[2] = hi ? y0 : a0;
                pa.u[3] = hi ? y1 : a1;
                const int ks = 2 * b + kk;
                __builtin_amdgcn_s_setprio(1);
#pragma unroll
                for (int df = 0; df < 2; df++) {
                    const short8v vf = *(const short8v*)(Vt[cur] +
                                                         (size_t)(df * 32 + sl) * KSTR +
                                                         ks * 16 + hi8);
                    O[df] = __builtin_amdgcn_mfma_f32_32x32x16_bf16(pa.v, vf,
                                                                    O[df], 0, 0, 0);
                }
                __builtin_amdgcn_s_setprio(0);
            }
        }
    }

    epi(s0);   // final segment (qb; or the only segment for s==1 blocks)
}

// ---------------------------------------------------------------------------
// Combine: rows < 1024 (qtiles 0..31) live entirely in partial 0;
// rows >= 1024 merge two partials. ctx bf16 written IN PLACE over O0.
// ---------------------------------------------------------------------------
__global__ __launch_bounds__(256) void combine(unsigned short* O01,   // aliased out
                                               const float* __restrict__ Lp) {
    const int i4 = (blockIdx.x * 256 + threadIdx.x) * 4;
    const int srow = i4 >> 11, hh = (i4 & 2047) >> 6;
    float l = Lp[(size_t)srow * NH + hh];
    ushort4v o0 = *(const ushort4v*)(O01 + i4);
    float acc[4];
#pragma unroll
    for (int j = 0; j < 4; j++) acc[j] = h2f(o0[j]);
    if (srow >= 1024) {      // wave-uniform per block (block spans 1024 elems)
        l += Lp[(size_t)S_LEN * NH + (size_t)srow * NH + hh];
        ushort4v o1 = *(const ushort4v*)(O01 + (size_t)S_LEN * DOUT + i4);
#pragma unroll
        for (int j = 0; j < 4; j++) acc[j] += h2f(o1[j]);
    }
    const float inv = 1.0f / l;
    ushort4v r;
#pragma unroll
    for (int j = 0; j < 4; j++) r[j] = f2bf(acc[j] * inv);
    *(ushort4v*)(O01 + i4) = r;
}

// ---------------------------------------------------------------------------
extern "C" void kernel_launch(void* const* d_in, const int* in_sizes, int n_in,
                              void* d_out, int out_size, void* d_ws, size_t ws_size,
                              hipStream_t stream) {
    const float* x    = (const float*)d_in[0];
    const float* cosb = (const float*)d_in[2];
    const float* sinb = (const float*)d_in[3];
    const float* Wq   = (const float*)d_in[4];
    const float* Wk   = (const float*)d_in[5];
    const float* Wv   = (const float*)d_in[6];
    const float* Wo   = (const float*)d_in[7];
    const float* qw   = (const float*)d_in[8];
    const float* kw   = (const float*)d_in[9];
    float* out = (float*)d_out;

    // ws layout (41.9 MB):
    //   W1  [0, 12.58M)      qkv weights^T bf16   -- dead after gemm_qkv
    //   XB  [12.58, 20.97M)  x bf16               -- dead after gemm_qkv
    //   WoT [20.97, 29.36M)  Wo^T bf16
    //   QKV [29.36, 41.94M)  q|k|v bf16
    // flash partials OVERLAY the dead W1+XB region:
    //   O0 [0, 8.39M) fp16 ; O1 [8.39, 16.78M) fp16 ; L0,L1 [16.78, 17.30M) fp32
    // combine writes ctx bf16 in place over O0; out-proj reads it from there.
    unsigned short* W1  = (unsigned short*)d_ws;
    unsigned short* XB  = W1 + (size_t)QKVN * DIN;
    unsigned short* WoT = XB + (size_t)S_LEN * DIN;
    unsigned short* QKV = WoT + (size_t)DIN * DOUT;
    unsigned short* Op  = (unsigned short*)d_ws;
    float*          Lp  = (float*)(Op + (size_t)2 * S_LEN * DOUT);
    unsigned short* CTX = Op;

    dim3 blk256(256);

    prep<<<dim3(14336), blk256, 0, stream>>>(Wq, Wk, Wv, Wo, x, W1, WoT, XB);

    gemm64<1><<<dim3(QKVN / 64, S_LEN / 128), blk256, 0, stream>>>(
        XB, W1, QKV, S_LEN, QKVN, DIN, qw, kw, cosb, sinb);

    // 512 uniform blocks: 8 kv-heads x 32 qtile-pairs x 2 chunks (17/16 tiles)
    flash_part<<<dim3(NKV * 32 * 2), blk256, 0, stream>>>(
        QKV, QKV + KOFF, QKV + VOFF, Op, Lp);

    combine<<<dim3(S_LEN * DOUT / 1024), blk256, 0, stream>>>(Op, Lp);

    gemm64<0><<<dim3(DIN / 64, S_LEN / 128), blk256, 0, stream>>>(
        CTX, WoT, out, S_LEN, DIN, DOUT, nullptr, nullptr, nullptr, nullptr);
}

// Round 4
// 235.355 us; speedup vs baseline: 1.1856x; 1.0051x over previous
//
#include <hip/hip_runtime.h>
#include <hip/hip_bf16.h>
#include <math.h>

#define S_LEN 2048
#define DIN   2048
#define NH    32
#define NKV   8
#define HD    64
#define DOUT  2048        // NH*HD
#define QKVN  3072        // DOUT + 2*KVD
#define KOFF  2048        // k col offset in qkv
#define VOFF  2560        // v col offset in qkv

typedef __attribute__((ext_vector_type(8))) short short8v;    // 8 bf16 (4 VGPRs)
typedef __attribute__((ext_vector_type(8))) unsigned short ushort8v;
typedef __attribute__((ext_vector_type(4))) unsigned short ushort4v;
typedef __attribute__((ext_vector_type(4))) float float4v;
typedef __attribute__((ext_vector_type(16))) float float16v;

__device__ __forceinline__ float bf2f(unsigned short u) {
    union { float f; unsigned u; } c; c.u = ((unsigned)u) << 16; return c.f;
}
__device__ __forceinline__ unsigned short f2bf(float f) {
    union { float f; unsigned u; } c; c.f = f;
    unsigned r = c.u + 0x7fffu + ((c.u >> 16) & 1u);   // RNE
    return (unsigned short)(r >> 16);
}
__device__ __forceinline__ unsigned short f2h(float f) {
    union { _Float16 h; unsigned short u; } c; c.h = (_Float16)f; return c.u;
}
__device__ __forceinline__ float h2f(unsigned short u) {
    union { _Float16 h; unsigned short u; } c; c.u = u; return (float)c.h;
}
__device__ __forceinline__ unsigned cvtpk(float lo, float hi) {
    unsigned r;
    asm("v_cvt_pk_bf16_f32 %0, %1, %2" : "=v"(r) : "v"(lo), "v"(hi));
    return r;
}
__device__ __forceinline__ float fexp2(float x) {           // guaranteed 1 trans op
    float r;
    asm("v_exp_f32 %0, %1" : "=v"(r) : "v"(x));
    return r;
}

// ---------------------------------------------------------------------------
// Fused preprocessing, ONE launch, grid sections:
//   [0, 6144)        : Wq|Wk|Wv fp32 [K][N] -> bf16 [N][K] into W1 (32x32 tiles)
//   [6144, 10240)    : Wo transpose into WoT
//   [10240, 14336)   : x fp32 -> bf16 cast into XB
// ---------------------------------------------------------------------------
__global__ __launch_bounds__(256) void prep(const float* __restrict__ Wq,
                                            const float* __restrict__ Wk,
                                            const float* __restrict__ Wv,
                                            const float* __restrict__ Wo,
                                            const float* __restrict__ x,
                                            unsigned short* __restrict__ W1,
                                            unsigned short* __restrict__ WoT,
                                            unsigned short* __restrict__ XB) {
    __shared__ float t[32][33];
    const int a = blockIdx.x;
    const int tx = threadIdx.x & 31, ty = threadIdx.x >> 5;
    if (a < 6144) {                       // qkv weights: grid (96, 64)
        const int n0 = (a % 96) * 32, k0 = (a / 96) * 32;
        const float* src; int nn0, Nsrc;
        if (n0 < KOFF)      { src = Wq; nn0 = n0;        Nsrc = DOUT; }
        else if (n0 < VOFF) { src = Wk; nn0 = n0 - KOFF; Nsrc = 512; }
        else                { src = Wv; nn0 = n0 - VOFF; Nsrc = 512; }
#pragma unroll
        for (int j = ty; j < 32; j += 8)
            t[j][tx] = src[(size_t)(k0 + j) * Nsrc + nn0 + tx];
        __syncthreads();
#pragma unroll
        for (int j = ty; j < 32; j += 8)
            W1[(size_t)(n0 + j) * DIN + k0 + tx] = f2bf(t[tx][j]);
    } else if (a < 10240) {               // Wo: grid (64, 64), K=DOUT rows, N=DIN
        const int b = a - 6144;
        const int n0 = (b % 64) * 32, k0 = (b / 64) * 32;
#pragma unroll
        for (int j = ty; j < 32; j += 8)
            t[j][tx] = Wo[(size_t)(k0 + j) * DIN + n0 + tx];
        __syncthreads();
#pragma unroll
        for (int j = ty; j < 32; j += 8)
            WoT[(size_t)(n0 + j) * DOUT + k0 + tx] = f2bf(t[tx][j]);
    } else {                              // x cast: 4096 blocks x 1024 elems
        const int i = (a - 10240) * 1024 + threadIdx.x * 4;
        float4 v = *(const float4*)(x + i);
        XB[i + 0] = f2bf(v.x); XB[i + 1] = f2bf(v.y);
        XB[i + 2] = f2bf(v.z); XB[i + 3] = f2bf(v.w);
    }
}

// ---------------------------------------------------------------------------
// bf16 MFMA GEMM v2: 128x64 tile, BK=64, 4 waves stacked in M (wave = 32x64).
//   * Double-buffered LDS + counted vmcnt (T3/T4): prefetch in flight across
//     the barrier. T2 XOR swizzle via pre-swizzled global source. setprio(1)
//     around MFMA cluster.
// FUSE=1: bf16 out + per-head RMSNorm+RoPE epilogue (block col = one head).
// FUSE=0: fp32 out, plain.
// ---------------------------------------------------------------------------
template <int FUSE>
__global__ __launch_bounds__(256) void gemm64(const unsigned short* __restrict__ A,
                                              const unsigned short* __restrict__ Bt,
                                              void* __restrict__ Cv, int M, int N, int K,
                                              const float* __restrict__ qnw,
                                              const float* __restrict__ knw,
                                              const float* __restrict__ cosb,
                                              const float* __restrict__ sinb) {
    __shared__ __attribute__((aligned(16))) unsigned short As[2 * 128 * 64];
    __shared__ __attribute__((aligned(16))) unsigned short Bs[2 * 64 * 64];
    const int tid = threadIdx.x, lane = tid & 63, w = tid >> 6;
    const int bm = blockIdx.y * 128, bn = blockIdx.x * 64;
    const int wm = w * 32;

    float4v acc[2][4];
#pragma unroll
    for (int i = 0; i < 2; i++)
#pragma unroll
        for (int j = 0; j < 4; j++) acc[i][j] = (float4v){0.f, 0.f, 0.f, 0.f};

    const int srow = lane >> 3;
    const int schk = (lane & 7) ^ srow;
    const unsigned short* Ag[4];
    const unsigned short* Bg[2];
#pragma unroll
    for (int g = 0; g < 4; g++)
        Ag[g] = A + (size_t)(bm + w * 32 + g * 8 + srow) * K + schk * 8;
#pragma unroll
    for (int g = 0; g < 2; g++)
        Bg[g] = Bt + (size_t)(bn + w * 16 + g * 8 + srow) * K + schk * 8;

    auto STAGE = [&](int t, int b) {
        const size_t ko = (size_t)t * 64;
        unsigned short* Ad = As + b * (128 * 64) + (w * 32) * 64;
        unsigned short* Bd = Bs + b * (64 * 64) + (w * 16) * 64;
#pragma unroll
        for (int g = 0; g < 4; g++)
            __builtin_amdgcn_global_load_lds(
                (const __attribute__((address_space(1))) void*)(Ag[g] + ko),
                (__attribute__((address_space(3))) void*)(Ad + g * 8 * 64), 16, 0, 0);
#pragma unroll
        for (int g = 0; g < 2; g++)
            __builtin_amdgcn_global_load_lds(
                (const __attribute__((address_space(1))) void*)(Bg[g] + ko),
                (__attribute__((address_space(3))) void*)(Bd + g * 8 * 64), 16, 0, 0);
    };

    const int frow = lane & 15, quad = lane >> 4, sw = frow & 7;
    const int NT = K >> 6;

    STAGE(0, 0);                                   // prologue: tile 0 -> buf 0

    for (int t = 0; t < NT; t++) {
        const int c = t & 1;
        if (t + 1 < NT) {
            STAGE(t + 1, c ^ 1);
            asm volatile("s_waitcnt vmcnt(6)" ::: "memory");   // tile t done
        } else {
            asm volatile("s_waitcnt vmcnt(0)" ::: "memory");
        }
        __builtin_amdgcn_s_barrier();
        __builtin_amdgcn_sched_barrier(0);

        const unsigned short* Ab = As + c * (128 * 64);
        const unsigned short* Bb = Bs + c * (64 * 64);
        short8v af[2][2], bf[4][2];
#pragma unroll
        for (int fm = 0; fm < 2; fm++)
#pragma unroll
            for (int ks = 0; ks < 2; ks++)
                af[fm][ks] = *(const short8v*)(Ab + (wm + fm * 16 + frow) * 64 +
                                               (((ks * 4 + quad) ^ sw) * 8));
#pragma unroll
        for (int fn = 0; fn < 4; fn++)
#pragma unroll
            for (int ks = 0; ks < 2; ks++)
                bf[fn][ks] = *(const short8v*)(Bb + (fn * 16 + frow) * 64 +
                                               (((ks * 4 + quad) ^ sw) * 8));
        __builtin_amdgcn_s_setprio(1);
#pragma unroll
        for (int ks = 0; ks < 2; ks++)
#pragma unroll
            for (int fm = 0; fm < 2; fm++)
#pragma unroll
                for (int fn = 0; fn < 4; fn++)
                    acc[fm][fn] = __builtin_amdgcn_mfma_f32_16x16x32_bf16(
                        af[fm][ks], bf[fn][ks], acc[fm][fn], 0, 0, 0);
        __builtin_amdgcn_s_setprio(0);

        if (t + 1 < NT) {
            asm volatile("s_waitcnt lgkmcnt(0)" ::: "memory");  // reads pulled
            __builtin_amdgcn_sched_barrier(0);
            __builtin_amdgcn_s_barrier();          // buf c free to overwrite
        }
    }

    const int quad4 = lane >> 4, col16 = lane & 15;
    if constexpr (FUSE == 1) {
        unsigned short* C = (unsigned short*)Cv;
        const int head = bn >> 6;                 // one head per block col
        if (head < 40) {
            const float* nw = (head < 32) ? qnw : knw;
            float wv[4];
#pragma unroll
            for (int fn = 0; fn < 4; fn++) wv[fn] = nw[fn * 16 + col16];
#pragma unroll
            for (int fm = 0; fm < 2; fm++)
#pragma unroll
                for (int r = 0; r < 4; r++) {
                    float x0 = acc[fm][0][r], x1 = acc[fm][1][r];
                    float x2 = acc[fm][2][r], x3 = acc[fm][3][r];
                    float ss = x0 * x0 + x1 * x1 + x2 * x2 + x3 * x3;
                    ss += __shfl_xor(ss, 1); ss += __shfl_xor(ss, 2);
                    ss += __shfl_xor(ss, 4); ss += __shfl_xor(ss, 8);
                    const float inv = rsqrtf(ss * (1.0f / 64.0f) + 1e-6f);
                    float xn[4] = {x0 * inv * wv[0], x1 * inv * wv[1],
                                   x2 * inv * wv[2], x3 * inv * wv[3]};
                    const int row = bm + wm + fm * 16 + quad4 * 4 + r;
                    const float* cr = cosb + (size_t)row * HD;
                    const float* sr = sinb + (size_t)row * HD;
#pragma unroll
                    for (int fn = 0; fn < 4; fn++) {
                        const float rot = (fn < 2) ? -xn[fn + 2] : xn[fn - 2];
                        const float res = xn[fn] * cr[fn * 16 + col16] +
                                          rot * sr[fn * 16 + col16];
                        C[(size_t)row * N + bn + fn * 16 + col16] = f2bf(res);
                    }
                }
        } else {
#pragma unroll
            for (int fm = 0; fm < 2; fm++)
#pragma unroll
                for (int fn = 0; fn < 4; fn++)
#pragma unroll
                    for (int r = 0; r < 4; r++)
                        C[(size_t)(bm + wm + fm * 16 + quad4 * 4 + r) * N +
                          bn + fn * 16 + col16] = f2bf(acc[fm][fn][r]);
        }
    } else {
        float* C = (float*)Cv;
#pragma unroll
        for (int fm = 0; fm < 2; fm++)
#pragma unroll
            for (int fn = 0; fn < 4; fn++)
#pragma unroll
                for (int r = 0; r < 4; r++)
                    C[(size_t)(bm + wm + fm * 16 + quad4 * 4 + r) * N +
                      bn + fn * 16 + col16] = acc[fm][fn][r];
    }
}

// ---------------------------------------------------------------------------
// MFMA flash attention v7 (causal, GQA), fixed-max softmax.
//   * Swapped QK^T (mfma(K, Q), 32x32x16), lane-local softmax, in-register
//     P->bf16 (cvt_pk). v7: lane<->lane^32 redistribution via
//     v_permlane32_swap_b32 (2 ops/frag, replaces 4 ds_bpermute + 4 cndmask).
//   * lsum on the matrix pipe: Lacc = mfma(pa, ones, Lacc) per P-frag
//     (4 MFMA/tile replace 32 VALU adds; same C-layout as O).
//   * 3 uniform chunks of 11 tiles per qtile-pair (33 = 3*11): 768 blocks =
//     3 blocks/CU = 3 waves/SIMD (LDS 45056*3 = 135KB, launch_bounds(256,3)).
//   * Partials: qa rows (<1024) -> 2 half-slots A0,A1; qb rows (>=1024) ->
//     3 half-slots B0..B2. 5 * 4.19MB = 20.97MB = exactly the dead W1+XB
//     region. L partials (5 * 128KB) live in d_out (dead until out-proj).
//   * Double-buffered K/V LDS, one barrier/tile, 2-deep reg prefetch.
// ---------------------------------------------------------------------------
#define KSTR 88    // K/V LDS row stride (shorts)

__global__ __launch_bounds__(256, 3) void flash_part(const unsigned short* __restrict__ qb,
                                                     const unsigned short* __restrict__ kb,
                                                     const unsigned short* __restrict__ vb,
                                                     unsigned short* __restrict__ Op,
                                                     float* __restrict__ Lp) {
    __shared__ __attribute__((aligned(16))) unsigned short Ks[2][64 * KSTR];
    __shared__ __attribute__((aligned(16))) unsigned short Vt[2][64 * KSTR];

    const int tid = threadIdx.x, lane = tid & 63, w = tid >> 6;
    const int sl = lane & 31, hi = lane >> 5, hi8 = hi * 8;
    const int bid = blockIdx.x;
    const int g = bid & 7;                    // kv head (== XCD id: L2 locality)
    const int p = (bid >> 3) & 31;            // pair index: qtiles p and 63-p
    const int c = bid >> 8;                   // chunk 0..2 (11 tiles each)
    const int h = g * 4 + w;

    const int s0a = p * 32, s0b = (63 - p) * 32;
    const int nta = (s0a + 95) >> 6;          // 1..16 (qa tiles; qb = 33-nta)
    const int W0 = c * 11;
    int nA = nta - W0;                        // qa tiles in this window
    nA = nA < 0 ? 0 : (nA > 11 ? 11 : nA);
    const bool owesA = (c < 2);               // chunks 0,1 write an A partial

    const float C1 = 0.18033688011112042f;    // 0.125 * log2(e)
    const float C2 = 12.262908856239697f;     // 8.5  * log2(e)

    // partial slots: A_c rows [0,1024), B_c rows [1024,2048)
    unsigned short* OhA = Op + (size_t)c * 1024 * DOUT;
    float*          LhA = Lp + (size_t)c * 1024 * NH;
    unsigned short* OhB = Op + (size_t)(2 + c) * 1024 * DOUT;
    float*          LhB = Lp + (size_t)(2 + c) * 1024 * NH;

    int seg = owesA ? 0 : 1;
    int s0 = seg == 0 ? s0a : s0b;

    // Q fragments (B-operand layout): lane holds Q[s0+sl][16*ksq + 8*hi + j]
    short8v qf[4];
#pragma unroll
    for (int ksq = 0; ksq < 4; ksq++)
        qf[ksq] = *(const short8v*)(qb + (size_t)(s0 + sl) * QKVN + h * HD +
                                    ksq * 16 + hi8);

    float16v O[2], Lacc;
#pragma unroll
    for (int df = 0; df < 2; df++)
#pragma unroll
        for (int r = 0; r < 16; r++) O[df][r] = 0.f;
#pragma unroll
    for (int r = 0; r < 16; r++) Lacc[r] = 0.f;

    short8v ones;
#pragma unroll
    for (int i = 0; i < 8; i++) ones[i] = (short)0x3F80;   // bf16 1.0

    // staging addresses
    const int kkey = tid >> 2, kch = tid & 3;     // K: 4 threads/key, 16 shorts
    const unsigned short* kg = kb + (size_t)kkey * QKVN + g * HD + kch * 16;
    const int kp = tid & 31, vdbb = tid >> 5;     // V: keys 2kp,2kp+1; dims vdbb*8..+8
    const unsigned short* vg0 = vb + (size_t)(2 * kp) * QKVN + g * HD + vdbb * 8;
    const unsigned short* vg1 = vg0 + QKVN;

    auto epi = [&](int sbase, unsigned short* Os, float* Ls, int roff) {
#pragma unroll
        for (int df = 0; df < 2; df++)
#pragma unroll
            for (int r = 0; r < 16; r++) {
                const int row = sbase + (r & 3) + 8 * (r >> 2) + 4 * hi - roff;
                Os[(size_t)row * DOUT + h * HD + df * 32 + sl] = f2h(O[df][r]);
            }
        if (sl == 0) {
#pragma unroll
            for (int r = 0; r < 16; r++) {
                const int row = sbase + (r & 3) + 8 * (r >> 2) + 4 * hi - roff;
                Ls[(size_t)row * NH + h] = Lacc[r];
            }
        }
    };
    auto zacc = [&]() {
#pragma unroll
        for (int df = 0; df < 2; df++)
#pragma unroll
            for (int r = 0; r < 16; r++) O[df][r] = 0.f;
#pragma unroll
        for (int r = 0; r < 16; r++) Lacc[r] = 0.f;
    };

    auto kt = [&](int jj) {                   // key-tile index for stream pos jj
        const int sj = W0 + jj;
        return (sj < nta) ? sj : (sj - nta);
    };

    ushort8v ka0, ka1, va0, va1;
    auto LOADREGS = [&](int it) {
        const size_t off = (size_t)it * 64 * QKVN;
        ka0 = *(const ushort8v*)(kg + off);
        ka1 = *(const ushort8v*)(kg + off + 8);
        va0 = *(const ushort8v*)(vg0 + off);
        va1 = *(const ushort8v*)(vg1 + off);
    };
    auto COMMIT = [&](int b) {
        unsigned short* kd = Ks[b] + kkey * KSTR + kch * 16;
        *(ushort8v*)kd = ka0;
        *(ushort8v*)(kd + 8) = ka1;
        union { ushort8v v; unsigned d[4]; } ua, ub;
        ua.v = va0; ub.v = va1;
        unsigned short* vd = Vt[b] + (size_t)(vdbb * 8) * KSTR + 2 * kp;
#pragma unroll
        for (int i = 0; i < 8; i++) {
            const unsigned sel = (i & 1) ? 0x07060302u : 0x05040100u;
            const unsigned word = __builtin_amdgcn_perm(ub.d[i >> 1], ua.d[i >> 1], sel);
            *(unsigned*)(vd + (size_t)i * KSTR) = word;
        }
    };

    // prologue: tile0 -> regs -> buf0; tile1 -> regs
    LOADREGS(kt(0));
    COMMIT(0);
    LOADREGS(kt(1));

#pragma unroll 1
    for (int jj = 0; jj < 11; jj++) {
        const int cur = jj & 1;
        __syncthreads();                    // buf[cur] committed; prev reads done
        if (jj + 1 < 11) COMMIT(cur ^ 1);   // regs hold tile jj+1
        if (jj + 2 < 11) LOADREGS(kt(jj + 2));
        if (seg == 0 && jj == nA) {         // qa -> qb boundary (flush A partial)
            epi(s0a, OhA, LhA, 0);
            zacc();
            s0 = s0b; seg = 1;
#pragma unroll
            for (int ksq = 0; ksq < 4; ksq++)
                qf[ksq] = *(const short8v*)(qb + (size_t)(s0b + sl) * QKVN +
                                            h * HD + ksq * 16 + hi8);
        }

        const int t0 = kt(jj) * 64;
        const bool edge = (t0 + 63 > s0);

#pragma unroll
        for (int b = 0; b < 2; b++) {
            short8v kf[4];
#pragma unroll
            for (int ksq = 0; ksq < 4; ksq++)
                kf[ksq] = *(const short8v*)(Ks[cur] + (32 * b + sl) * KSTR +
                                            ksq * 16 + hi8);
            float16v sct;
#pragma unroll
            for (int r = 0; r < 16; r++) sct[r] = 0.f;
            __builtin_amdgcn_s_setprio(1);
#pragma unroll
            for (int ksq = 0; ksq < 4; ksq++)
                sct = __builtin_amdgcn_mfma_f32_32x32x16_bf16(kf[ksq], qf[ksq],
                                                              sct, 0, 0, 0);
            __builtin_amdgcn_s_setprio(0);
#pragma unroll
            for (int r = 0; r < 16; r++) {
                float arg = sct[r] * C1 - C2;
                if (edge) {
                    const int kglob = t0 + 32 * b + (r & 3) + 8 * (r >> 2) + 4 * hi;
                    arg = (kglob <= s0 + sl) ? arg : -100.f;
                }
                sct[r] = fexp2(arg);
            }
            unsigned pk[8];
#pragma unroll
            for (int i = 0; i < 8; i++) pk[i] = cvtpk(sct[2 * i], sct[2 * i + 1]);
#pragma unroll
            for (int kk = 0; kk < 2; kk++) {
                unsigned x0 = pk[4 * kk + 0], x1 = pk[4 * kk + 1];
                unsigned y0 = pk[4 * kk + 2], y1 = pk[4 * kk + 3];
                // halves swap: x' = {x_lo, y_lo}, y' = {x_hi, y_hi}
                asm("v_permlane32_swap_b32 %0, %1" : "+v"(x0), "+v"(y0));
                asm("v_permlane32_swap_b32 %0, %1" : "+v"(x1), "+v"(y1));
                union { unsigned u[4]; short8v v; } pa;
                pa.u[0] = x0; pa.u[1] = x1; pa.u[2] = y0; pa.u[3] = y1;
                const int ks = 2 * b + kk;
                __builtin_amdgcn_s_setprio(1);
#pragma unroll
                for (int df = 0; df < 2; df++) {
                    const short8v vf = *(const short8v*)(Vt[cur] +
                                                         (size_t)(df * 32 + sl) * KSTR +
                                                         ks * 16 + hi8);
                    O[df] = __builtin_amdgcn_mfma_f32_32x32x16_bf16(pa.v, vf,
                                                                    O[df], 0, 0, 0);
                }
                Lacc = __builtin_amdgcn_mfma_f32_32x32x16_bf16(pa.v, ones,
                                                               Lacc, 0, 0, 0);
                __builtin_amdgcn_s_setprio(0);
            }
        }
    }

    if (seg == 0) {            // window was all-qa: flush A, B partial = zeros
        epi(s0a, OhA, LhA, 0);
        zacc();
    }
    epi(s0b, OhB, LhB, 1024);  // every block writes its B partial
}

// ---------------------------------------------------------------------------
// Combine: rows < 1024 merge A0+A1; rows >= 1024 merge B0+B1+B2.
// ctx (bf16) written to CTX (the dead QKV region).
// ---------------------------------------------------------------------------
__global__ __launch_bounds__(256) void combine(const unsigned short* __restrict__ Op,
                                               const float* __restrict__ Lp,
                                               unsigned short* __restrict__ CTX) {
    const int i4 = (blockIdx.x * 256 + threadIdx.x) * 4;
    const int row = i4 >> 11, hh = (i4 & 2047) >> 6;
    float acc[4];
    float l;
    if (row < 1024) {          // wave-uniform (block spans half a row)
        ushort4v a0 = *(const ushort4v*)(Op + i4);
        ushort4v a1 = *(const ushort4v*)(Op + (size_t)1024 * DOUT + i4);
#pragma unroll
        for (int j = 0; j < 4; j++) acc[j] = h2f(a0[j]) + h2f(a1[j]);
        l = Lp[(size_t)row * NH + hh] + Lp[(size_t)(1024 + row) * NH + hh];
    } else {
        const size_t j4 = (size_t)(row - 1024) * DOUT + (i4 & 2047);
        ushort4v b0 = *(const ushort4v*)(Op + (size_t)2 * 1024 * DOUT + j4);
        ushort4v b1 = *(const ushort4v*)(Op + (size_t)3 * 1024 * DOUT + j4);
        ushort4v b2 = *(const ushort4v*)(Op + (size_t)4 * 1024 * DOUT + j4);
#pragma unroll
        for (int j = 0; j < 4; j++) acc[j] = h2f(b0[j]) + h2f(b1[j]) + h2f(b2[j]);
        const size_t lr = (size_t)(row - 1024) * NH + hh;
        l = Lp[(size_t)2 * 1024 * NH + lr] + Lp[(size_t)3 * 1024 * NH + lr] +
            Lp[(size_t)4 * 1024 * NH + lr];
    }
    const float inv = 1.0f / l;
    ushort4v r;
#pragma unroll
    for (int j = 0; j < 4; j++) r[j] = f2bf(acc[j] * inv);
    *(ushort4v*)(CTX + i4) = r;
}

// ---------------------------------------------------------------------------
extern "C" void kernel_launch(void* const* d_in, const int* in_sizes, int n_in,
                              void* d_out, int out_size, void* d_ws, size_t ws_size,
                              hipStream_t stream) {
    const float* x    = (const float*)d_in[0];
    const float* cosb = (const float*)d_in[2];
    const float* sinb = (const float*)d_in[3];
    const float* Wq   = (const float*)d_in[4];
    const float* Wk   = (const float*)d_in[5];
    const float* Wv   = (const float*)d_in[6];
    const float* Wo   = (const float*)d_in[7];
    const float* qw   = (const float*)d_in[8];
    const float* kw   = (const float*)d_in[9];
    float* out = (float*)d_out;

    // ws layout (41.9 MB):
    //   W1  [0, 12.58M)      qkv weights^T bf16   -- dead after gemm_qkv
    //   XB  [12.58, 20.97M)  x bf16               -- dead after gemm_qkv
    //   WoT [20.97, 29.36M)  Wo^T bf16            -- live until out-proj
    //   QKV [29.36, 41.94M)  q|k|v bf16           -- dead after flash
    // flash partials OVERLAY W1+XB (exactly 20.97M):
    //   A0,A1 (qa rows <1024): 2 x 4.19M fp16 ; B0..B2 (qb rows >=1024): 3 x 4.19M
    // L partials (5 x 128K fp32) live in d_out (scratch until out-proj).
    // combine writes ctx bf16 into the dead QKV region; out-proj reads it.
    unsigned short* W1  = (unsigned short*)d_ws;
    unsigned short* XB  = W1 + (size_t)QKVN * DIN;
    unsigned short* WoT = XB + (size_t)S_LEN * DIN;
    unsigned short* QKV = WoT + (size_t)DIN * DOUT;
    unsigned short* Op  = (unsigned short*)d_ws;
    float*          Lp  = (float*)d_out;
    unsigned short* CTX = QKV;

    dim3 blk256(256);

    prep<<<dim3(14336), blk256, 0, stream>>>(Wq, Wk, Wv, Wo, x, W1, WoT, XB);

    gemm64<1><<<dim3(QKVN / 64, S_LEN / 128), blk256, 0, stream>>>(
        XB, W1, QKV, S_LEN, QKVN, DIN, qw, kw, cosb, sinb);

    // 768 uniform blocks: 8 kv-heads x 32 qtile-pairs x 3 chunks (11 tiles each)
    flash_part<<<dim3(NKV * 32 * 3), blk256, 0, stream>>>(
        QKV, QKV + KOFF, QKV + VOFF, Op, Lp);

    combine<<<dim3(S_LEN * DOUT / 1024), blk256, 0, stream>>>(Op, Lp, CTX);

    gemm64<0><<<dim3(DIN / 64, S_LEN / 128), blk256, 0, stream>>>(
        CTX, WoT, out, S_LEN, DIN, DOUT, nullptr, nullptr, nullptr, nullptr);
}